// Round 3
// baseline (3590.410 us; speedup 1.0000x reference)
//
#include <hip/hip_runtime.h>

// TemporalAttentionDecoder_three_step: B=512, T=64, M=P=256. in f32, out f32.
// R9:  1120us (8 waves/CU, 1x traffic).  R10: 1108us (16 waves/CU, 1x traffic).
// R8 (2 domains, 2x traffic) 1192. Insensitive to occupancy/traffic/domains ->
// bottleneck = per-wave dependent chains in bulk-synchronous phases (lockstep
// stalls; VGPR=64 gave compiler no prefetch room; 6 live pointers x 2 VALU
// incr/iter).
// R11: (1) weights repacked per-thread-contiguous: thread j=(q<<8)|n owns ONE
//      768B chunk [Wd k-quarter | gate-a k-half | gate-b k-half], single base,
//      all loads via immediate offsets -> zero per-iter addr math, easy MLP.
//      (2) 4-way split q: Wd k-range [128q,128q+128); gates {2(q>>1),+1} with
//      k-half (q&1) -> state H8s coincide for q<2. Weight bytes still read
//      once per block per step. (3) softmax folded into B2: each B2 wave
//      redundantly computes the 64-wide softmax into a private beta buffer ->
//      4 barriers/step (was 5). (4) gate partials f16 LDS, x1 quarters f32,
//      folded in B1/G. LDS 158.6KB, 1024 thr, NROW=2, grid 256.
// f32 state: creg (j<256); f16: h,c,y1,E,ct,weights,gate-partials.

typedef unsigned short u16;
typedef unsigned int u32;
typedef _Float16 half_t;
typedef half_t h2 __attribute__((ext_vector_type(2)));

#define BB 512
#define TT 64
#define MM 256
#define YS 264   // y1l row stride (u16); measured conflict-free (R6/R7)
#define ES 68    // e16T row stride (u16); 2-way (free)
#define NROW 2
#define NTH 1024

// ws layout (u16):
//  stream chunks [1024 j][384], j=(q<<8)|n:
//    [  0..127]: Wd[n][q*128 + r]                       (r=0..127)
//    [128..255]: Whh[n+256*(2*(q>>1)  )][(q&1)*128 + r]
//    [256..383]: Whh[n+256*(2*(q>>1)+1)][(q&1)*128 + r]
//  Wy chunks @393216: [512 c][256], c=(kh<<8)|n: Wy[n][kh*256 + r]
#define WY16_OFF  393216
#define WQ_ELEMS  524288
#define WQ_BYTES  (WQ_ELEMS * 2)

struct H8 { h2 p[4]; };   // 16B = 8 f16

#if defined(__has_builtin)
#if __has_builtin(__builtin_amdgcn_fdot2)
#define FDOT2(a, b, c) __builtin_amdgcn_fdot2((a), (b), (c), false)
#endif
#endif
#ifndef FDOT2
__device__ __forceinline__ float FDOT2(h2 a, h2 b, float c) {
  return c + (float)a[0] * (float)b[0] + (float)a[1] * (float)b[1];
}
#endif

__device__ __forceinline__ float dot8(const H8 w, const H8 a, float acc) {
  acc = FDOT2(w.p[0], a.p[0], acc);
  acc = FDOT2(w.p[1], a.p[1], acc);
  acc = FDOT2(w.p[2], a.p[2], acc);
  acc = FDOT2(w.p[3], a.p[3], acc);
  return acc;
}
__device__ __forceinline__ u16 f2h(float f) {
  union { half_t h; u16 u; } x; x.h = (half_t)f; return x.u;
}
__device__ __forceinline__ float h2f(u16 u) {
  union { u16 u; half_t h; } x; x.u = u; return (float)x.h;
}
__device__ __forceinline__ void unpackH8(const H8 v, float f[8]) {
#pragma unroll
  for (int i = 0; i < 8; ++i) f[i] = (float)v.p[i >> 1][i & 1];
}
__device__ __forceinline__ void ldf8(const float* p, float f[8]) {
  float4 a = *(const float4*)p;
  float4 b = *(const float4*)(p + 4);
  f[0]=a.x; f[1]=a.y; f[2]=a.z; f[3]=a.w;
  f[4]=b.x; f[5]=b.y; f[6]=b.z; f[7]=b.w;
}
__device__ __forceinline__ float tanh_fast(float x) {
  float e = __builtin_amdgcn_exp2f(x * 2.885390081777927f);
  return 1.0f - 2.0f * __builtin_amdgcn_rcpf(1.0f + e);
}
__device__ __forceinline__ float sigmoid_fast(float x) {
  float e = __builtin_amdgcn_exp2f(x * -1.4426950408889634f);
  return __builtin_amdgcn_rcpf(1.0f + e);
}

// ---- prep: f32 -> f16, per-thread-contiguous chunks ----
__global__ __launch_bounds__(256) void prep_kernel(
    const float* __restrict__ Wd, const float* __restrict__ Whh,
    const float* __restrict__ Wy, u16* __restrict__ o) {
  int u = blockIdx.x * 256 + threadIdx.x;   // 0..524287
  float v;
  if (u < WY16_OFF) {
    int c = u / 384, s = u % 384;
    int q = c >> 8, n = c & 255;
    int part = s >> 7, rem = s & 127;
    if (part == 0) {
      v = Wd[n * 512 + q * 128 + rem];
    } else {
      int g = 2 * (q >> 1) + (part - 1);
      v = Whh[(n + 256 * g) * 256 + (q & 1) * 128 + rem];
    }
  } else {
    int w = u - WY16_OFF;
    int c = w >> 8, rem = w & 255;
    int kh = c >> 8, n = c & 255;
    v = Wy[n * 512 + kh * 256 + rem];
  }
  o[u] = f2h(v);
}

template <int WQ>
__global__ __launch_bounds__(NTH, 4) void scan_kernel(
    const float* __restrict__ E,      // (B,T,M)
    const float* __restrict__ yin,    // (B,T,1)
    const float* __restrict__ tar,    // (B,2)
    const int*   __restrict__ train,  // (1)
    const void*  __restrict__ Wd_q,   // WQ1: stream chunk base | WQ0: Wd f32
    const float* __restrict__ Wd_b,
    const float* __restrict__ Ud_w,   // (256,256) f32
    const float* __restrict__ vd_w,
    const float* __restrict__ wt_w,   // (257)
    const float* __restrict__ wt_b,
    const void*  __restrict__ Wy_q,   // WQ1: Wy chunk base | WQ0: Wy f32
    const float* __restrict__ Wy_b,
    const float* __restrict__ vy_w,
    const float* __restrict__ vy_b,
    const float* __restrict__ Wih,    // (1024)
    const void*  __restrict__ Whh_q,  // WQ0 only: Whh f32
    const float* __restrict__ bih,
    const float* __restrict__ bhh,
    float* __restrict__ out)          // (3*B)
{
  __shared__ __align__(16) u16   y1l[NROW][TT * YS];   // 66KB f16 y1
  __shared__ __align__(16) u16   e16T[NROW][MM * ES];  // 68KB f16 E^T
  __shared__ __align__(16) u32   hs16[NROW][256];      // h pairs [0,128), c [128,256)
  __shared__ __align__(16) u32   ctx16p[NROW][128];    // ct f16 pairs
  __shared__ __align__(16) float px1[8 * MM];          // x1 quarters (r*4+q)*256+n; head reuse
  __shared__ __align__(16) u16   pgs[16 * MM];         // gate partials ((q*2+ab)*2+r)*256+n
  __shared__ __align__(16) float lpart[NROW][8][TT];
  __shared__ __align__(16) u16   betas16[8][TT];       // per-wave beta copies
  __shared__ __align__(16) float ysh[NROW][TT];
  __shared__ float red[16];
  __shared__ float sc[NROW];

  const int j   = threadIdx.x;         // 0..1023
  const int n   = j & 255;             // output index
  const int q   = j >> 8;              // k/gate group 0..3 (wave-aligned)
  const int wv  = j >> 6;              // wave 0..15
  const int b0  = blockIdx.x * NROW;   // batch rows b0, b0+1

  if (j < 512) ((u32*)hs16)[j] = 0;
  float creg0 = 0.f, creg1 = 0.f;      // live in j<256 threads

  // gate constants (consumed by j<256)
  const float wih0 = Wih[n],       wih1 = Wih[n + 256];
  const float wih2 = Wih[n + 512], wih3 = Wih[n + 768];
  const float bb0 = bih[n]       + bhh[n];
  const float bb1 = bih[n + 256] + bhh[n + 256];
  const float bb2 = bih[n + 512] + bhh[n + 512];
  const float bb3 = bih[n + 768] + bhh[n + 768];
  const float wtM = wt_w[MM], wtb = wt_b[0];

  // ---- stage yin rows ----
  if (j < NROW * TT)
    ysh[j >> 6][j & 63] = yin[(size_t)(b0 + (j >> 6)) * TT + (j & 63)];

  // ---- stage E^T (f16) into LDS for both rows ----
  {
    const float* __restrict__ Eb0 = E + (size_t)b0 * TT * MM;
    for (int i = j; i < NROW * TT * MM; i += NTH) {
      int r = i >> 14;
      int idx = i & 16383;
      int t = idx >> 8, m = idx & 255;
      e16T[r][m * ES + t] = f2h(Eb0[i]);
    }
  }

  // ---- y1 into LDS: thread (q,n): row q>>1, t-half q&1, column n ----
  {
    const int rs = q >> 1, ths = q & 1;
    const float* __restrict__ Eb = E + (size_t)(b0 + rs) * TT * MM;
    const float* __restrict__ Uj = Ud_w + (size_t)n * MM;
    for (int t0 = ths * 32; t0 < ths * 32 + 32; t0 += 16) {
      float acc[16];
#pragma unroll
      for (int i = 0; i < 16; ++i) acc[i] = 0.f;
      for (int m0 = 0; m0 < MM; m0 += 8) {
        float w[8]; ldf8(Uj + m0, w);
#pragma unroll
        for (int tt = 0; tt < 16; ++tt) {
          float e[8]; ldf8(Eb + (size_t)(t0 + tt) * MM + m0, e);
#pragma unroll
          for (int mm = 0; mm < 8; ++mm) acc[tt] = fmaf(e[mm], w[mm], acc[tt]);
        }
      }
#pragma unroll
      for (int tt = 0; tt < 16; ++tt)
        y1l[rs][(t0 + tt) * YS + n] = f2h(acc[tt]);
    }
  }
  __syncthreads();

  // ---- gates: torch LSTMCell order i,f,g,o; j<256, both rows ----
  auto gates_apply = [&](int r, float gi, float gf, float gg, float go,
                         float ytil) {
    gi += ytil * wih0 + bb0;
    gf += ytil * wih1 + bb1;
    gg += ytil * wih2 + bb2;
    go += ytil * wih3 + bb3;
    float& cr = r ? creg1 : creg0;
    float c = sigmoid_fast(gf) * cr + sigmoid_fast(gi) * tanh_fast(gg);
    float h = sigmoid_fast(go) * tanh_fast(c);
    cr = c;
    u16* hsu = (u16*)hs16[r];
    hsu[n] = f2h(h);
    hsu[256 + n] = f2h(c);
  };

  // ---- combine gate partials from pgs ----
  auto gate_combine = [&](int r, float& gi, float& gf, float& gg, float& go) {
    gi = h2f(pgs[(0 * 2 + r) * 256 + n]) + h2f(pgs[(2 * 2 + r) * 256 + n]);
    gf = h2f(pgs[(1 * 2 + r) * 256 + n]) + h2f(pgs[(3 * 2 + r) * 256 + n]);
    gg = h2f(pgs[(4 * 2 + r) * 256 + n]) + h2f(pgs[(6 * 2 + r) * 256 + n]);
    go = h2f(pgs[(5 * 2 + r) * 256 + n]) + h2f(pgs[(7 * 2 + r) * 256 + n]);
  };
  // pgs index: ((q*2+ab)*2+r)*256+n; gate0: (q0,a)+(q1,a) -> slots 0,2
  //            gate1: (q0,b)+(q1,b) -> 1,3 ; gate2: (q2,a)+(q3,a) -> 4,6
  //            gate3: (q2,b)+(q3,b) -> 5,7

  // ---- head: j<512: kh=j>>8 selects h-seg / ct-seg; both rows ----
  auto head_store = [&](int outIdx) {
    if (j < 512) {
      const int kh = j >> 8, nn = j & 255;
      float p0 = 0.f, p1 = 0.f;
      const u32* s0 = kh ? ctx16p[0] : hs16[0];
      const u32* s1 = kh ? ctx16p[1] : hs16[1];
      if (WQ) {
        const u16* pw = (const u16*)Wy_q + ((size_t)(kh * 256 + nn)) * 256;
#pragma unroll 4
        for (int i = 0; i < 32; ++i) {
          H8 w = *(const H8*)(pw + i * 8);
          H8 a0 = *(const H8*)&s0[i * 4];
          H8 a1 = *(const H8*)&s1[i * 4];
          p0 = dot8(w, a0, p0);
          p1 = dot8(w, a1, p1);
        }
      } else {
        const float* W = (const float*)Wy_q + (size_t)nn * 512 + kh * 256;
#pragma unroll 2
        for (int i = 0; i < 32; ++i) {
          H8 a0v = *(const H8*)&s0[i * 4];
          H8 a1v = *(const H8*)&s1[i * 4];
          float a0[8], a1[8]; unpackH8(a0v, a0); unpackH8(a1v, a1);
          float w[8]; ldf8(W + i * 8, w);
#pragma unroll
          for (int m = 0; m < 8; ++m) {
            p0 = fmaf(a0[m], w[m], p0);
            p1 = fmaf(a1[m], w[m], p1);
          }
        }
      }
      px1[(kh * 2 + 0) * 256 + nn] = p0;
      px1[(kh * 2 + 1) * 256 + nn] = p1;
    }
    __syncthreads();
    if (j < 256) {
      float q0 = (px1[n] + px1[2 * 256 + n] + Wy_b[n]) * vy_w[n];
      float q1 = (px1[1 * 256 + n] + px1[3 * 256 + n] + Wy_b[n]) * vy_w[n];
#pragma unroll
      for (int off = 32; off; off >>= 1) {
        q0 += __shfl_xor(q0, off, 64);
        q1 += __shfl_xor(q1, off, 64);
      }
      if ((j & 63) == 0) { red[wv] = q0; red[4 + wv] = q1; }
    }
    __syncthreads();
    if (j == 0) {
      float o0 = red[0] + red[1] + red[2] + red[3] + vy_b[0];
      float o1 = red[4] + red[5] + red[6] + red[7] + vy_b[0];
      out[(size_t)outIdx * BB + b0] = o0;
      out[(size_t)outIdx * BB + b0 + 1] = o1;
      sc[0] = o0; sc[1] = o1;
    }
    __syncthreads();
  };

  const int cw = q * 64;          // concat-state word base (Wd part)
  const int gw = (q & 1) * 64;    // gate-h word base

  // ================= scan over T steps =================
  for (int step = 0; step < TT; ++step) {
    // ---- S: per-thread contiguous chunk, imm-offset loads ----
    {
      float ax0 = 0.f, ax1 = 0.f;
      float ga0 = 0.f, ga1 = 0.f, gb0 = 0.f, gb1 = 0.f;
      if (WQ) {
        const u16* base = (const u16*)Wd_q + (size_t)j * 384;
        const u32* h0p = hs16[0];
        const u32* h1p = hs16[1];
#pragma unroll 4
        for (int i = 0; i < 16; ++i) {
          H8 wd = *(const H8*)(base + i * 8);
          H8 wa = *(const H8*)(base + 128 + i * 8);
          H8 wb = *(const H8*)(base + 256 + i * 8);
          H8 cs0 = *(const H8*)&h0p[cw + i * 4];
          H8 cs1 = *(const H8*)&h1p[cw + i * 4];
          H8 hh0 = *(const H8*)&h0p[gw + i * 4];
          H8 hh1 = *(const H8*)&h1p[gw + i * 4];
          ax0 = dot8(wd, cs0, ax0); ax1 = dot8(wd, cs1, ax1);
          ga0 = dot8(wa, hh0, ga0); ga1 = dot8(wa, hh1, ga1);
          gb0 = dot8(wb, hh0, gb0); gb1 = dot8(wb, hh1, gb1);
        }
      } else {
        const int gsel = 2 * (q >> 1);
        const float* pwd = (const float*)Wd_q + (size_t)n * 512 + q * 128;
        const float* pwa = (const float*)Whh_q +
                           ((size_t)(n + 256 * gsel)) * 256 + (q & 1) * 128;
        const float* pwb = pwa + 256 * 256;
#pragma unroll 2
        for (int i = 0; i < 16; ++i) {
          H8 cs0v = *(const H8*)&hs16[0][cw + i * 4];
          H8 cs1v = *(const H8*)&hs16[1][cw + i * 4];
          H8 hh0v = *(const H8*)&hs16[0][gw + i * 4];
          H8 hh1v = *(const H8*)&hs16[1][gw + i * 4];
          float c0[8], c1[8], h0f[8], h1f[8];
          unpackH8(cs0v, c0); unpackH8(cs1v, c1);
          unpackH8(hh0v, h0f); unpackH8(hh1v, h1f);
          float wd8[8], wa8[8], wb8[8];
          ldf8(pwd + i * 8, wd8); ldf8(pwa + i * 8, wa8); ldf8(pwb + i * 8, wb8);
#pragma unroll
          for (int m = 0; m < 8; ++m) {
            ax0 = fmaf(c0[m], wd8[m], ax0); ax1 = fmaf(c1[m], wd8[m], ax1);
            ga0 = fmaf(h0f[m], wa8[m], ga0); ga1 = fmaf(h1f[m], wa8[m], ga1);
            gb0 = fmaf(h0f[m], wb8[m], gb0); gb1 = fmaf(h1f[m], wb8[m], gb1);
          }
        }
      }
      if (q == 0) { float b = Wd_b[n]; ax0 += b; ax1 += b; }
      px1[(0 * 4 + q) * 256 + n] = ax0;
      px1[(1 * 4 + q) * 256 + n] = ax1;
      pgs[((q * 2 + 0) * 2 + 0) * 256 + n] = f2h(ga0);
      pgs[((q * 2 + 0) * 2 + 1) * 256 + n] = f2h(ga1);
      pgs[((q * 2 + 1) * 2 + 0) * 256 + n] = f2h(gb0);
      pgs[((q * 2 + 1) * 2 + 1) * 256 + n] = f2h(gb1);
    }
    __syncthreads();

    // ---- B1: l[t] eighth-partials; thread = (r, e8, t); 32 m each ----
    {
      const int r = j >> 9, e8 = (j >> 6) & 7, t = j & 63;
      const int mb = e8 * 32;
      const u16* __restrict__ yrow = &y1l[r][t * YS + mb];
      const float* p0 = &px1[(r * 4 + 0) * 256 + mb];
      const float* p1 = &px1[(r * 4 + 1) * 256 + mb];
      const float* p2 = &px1[(r * 4 + 2) * 256 + mb];
      const float* p3 = &px1[(r * 4 + 3) * 256 + mb];
      const float* vp = vd_w + mb;
      float lp = 0.f;
#pragma unroll
      for (int m0 = 0; m0 < 32; m0 += 8) {
        float xa[8], xb[8], xc[8], xd[8], vf[8], yf[8];
        ldf8(p0 + m0, xa); ldf8(p1 + m0, xb);
        ldf8(p2 + m0, xc); ldf8(p3 + m0, xd);
        H8 yv = *(const H8*)(yrow + m0); unpackH8(yv, yf);
        ldf8(vp + m0, vf);
#pragma unroll
        for (int mm = 0; mm < 8; ++mm) {
          float z = tanh_fast(xa[mm] + xb[mm] + xc[mm] + xd[mm] + yf[mm]);
          lp = fmaf(z, vf[mm], lp);
        }
      }
      lpart[r][e8][t] = lp;
    }
    __syncthreads();

    // ---- B2': per-wave redundant softmax + ct + ytil reduce (j<512) ----
    if (j < 512) {
      const int r = j >> 8, lane = j & 63;
      float l = lpart[r][0][lane] + lpart[r][1][lane] + lpart[r][2][lane] +
                lpart[r][3][lane] + lpart[r][4][lane] + lpart[r][5][lane] +
                lpart[r][6][lane] + lpart[r][7][lane];
      float mx = l;
#pragma unroll
      for (int off = 32; off; off >>= 1) mx = fmaxf(mx, __shfl_xor(mx, off, 64));
      float e = __builtin_amdgcn_exp2f((l - mx) * 1.4426950408889634f);
      float sm = e;
#pragma unroll
      for (int off = 32; off; off >>= 1) sm += __shfl_xor(sm, off, 64);
      betas16[wv][lane] = f2h(e * __builtin_amdgcn_rcpf(sm));
      asm volatile("s_waitcnt lgkmcnt(0)" ::: "memory");
      const u16* __restrict__ bp = betas16[wv];
      const u16* __restrict__ ep = &e16T[r][n * ES];
      float acc = 0.f;
#pragma unroll
      for (int t0 = 0; t0 < TT; t0 += 8) {
        H8 bv = *(const H8*)(bp + t0);
        h2 e0 = *(const h2*)(ep + t0);
        h2 e1 = *(const h2*)(ep + t0 + 2);
        h2 e2 = *(const h2*)(ep + t0 + 4);
        h2 e3 = *(const h2*)(ep + t0 + 6);
        acc = FDOT2(bv.p[0], e0, acc);
        acc = FDOT2(bv.p[1], e1, acc);
        acc = FDOT2(bv.p[2], e2, acc);
        acc = FDOT2(bv.p[3], e3, acc);
      }
      ((u16*)ctx16p[r])[n] = f2h(acc);
      float p = acc * wt_w[n];
#pragma unroll
      for (int off = 32; off; off >>= 1) p += __shfl_xor(p, off, 64);
      if ((j & 63) == 0) red[wv] = p;   // wv 0..3 -> r0, 4..7 -> r1
    }
    __syncthreads();

    // ---- G: combine gate partials + gates (j<256, both rows) ----
    if (j < 256) {
      float yt0 = red[0] + red[1] + red[2] + red[3] + ysh[0][step] * wtM + wtb;
      float yt1 = red[4] + red[5] + red[6] + red[7] + ysh[1][step] * wtM + wtb;
      float gi, gf, gg, go;
      gate_combine(0, gi, gf, gg, go);
      gates_apply(0, gi, gf, gg, go, yt0);
      gate_combine(1, gi, gf, gg, go);
      gates_apply(1, gi, gf, gg, go, yt1);
    }
    __syncthreads();
  }

  // ================= finals =================
  // ctdot from final f16 ct (same precision path as head)
  if (j < 512) {
    const int r = j >> 8;
    float p = h2f(((const u16*)ctx16p[r])[n]) * wt_w[n];
#pragma unroll
    for (int off = 32; off; off >>= 1) p += __shfl_xor(p, off, 64);
    if ((j & 63) == 0) red[wv] = p;
  }
  __syncthreads();
  const float ctd0 = red[0] + red[1] + red[2] + red[3];
  const float ctd1 = red[4] + red[5] + red[6] + red[7];

  head_store(0);  // y_Tp1 (sc[] holds it for train==0 feedback)

  const int tr = train[0];
  for (int e = 0; e < 2; ++e) {
    // ---- gate-only stream (all threads), chunk offsets 128.. ----
    {
      float ga0 = 0.f, ga1 = 0.f, gb0 = 0.f, gb1 = 0.f;
      if (WQ) {
        const u16* base = (const u16*)Wd_q + (size_t)j * 384;
        const u32* h0p = hs16[0];
        const u32* h1p = hs16[1];
#pragma unroll 4
        for (int i = 0; i < 16; ++i) {
          H8 wa = *(const H8*)(base + 128 + i * 8);
          H8 wb = *(const H8*)(base + 256 + i * 8);
          H8 hh0 = *(const H8*)&h0p[gw + i * 4];
          H8 hh1 = *(const H8*)&h1p[gw + i * 4];
          ga0 = dot8(wa, hh0, ga0); ga1 = dot8(wa, hh1, ga1);
          gb0 = dot8(wb, hh0, gb0); gb1 = dot8(wb, hh1, gb1);
        }
      } else {
        const int gsel = 2 * (q >> 1);
        const float* pwa = (const float*)Whh_q +
                           ((size_t)(n + 256 * gsel)) * 256 + (q & 1) * 128;
        const float* pwb = pwa + 256 * 256;
#pragma unroll 2
        for (int i = 0; i < 16; ++i) {
          H8 hh0v = *(const H8*)&hs16[0][gw + i * 4];
          H8 hh1v = *(const H8*)&hs16[1][gw + i * 4];
          float h0f[8], h1f[8]; unpackH8(hh0v, h0f); unpackH8(hh1v, h1f);
          float wa8[8], wb8[8];
          ldf8(pwa + i * 8, wa8); ldf8(pwb + i * 8, wb8);
#pragma unroll
          for (int m = 0; m < 8; ++m) {
            ga0 = fmaf(h0f[m], wa8[m], ga0); ga1 = fmaf(h1f[m], wa8[m], ga1);
            gb0 = fmaf(h0f[m], wb8[m], gb0); gb1 = fmaf(h1f[m], wb8[m], gb1);
          }
        }
      }
      pgs[((q * 2 + 0) * 2 + 0) * 256 + n] = f2h(ga0);
      pgs[((q * 2 + 0) * 2 + 1) * 256 + n] = f2h(ga1);
      pgs[((q * 2 + 1) * 2 + 0) * 256 + n] = f2h(gb0);
      pgs[((q * 2 + 1) * 2 + 1) * 256 + n] = f2h(gb1);
    }
    __syncthreads();
    if (j < 256) {
      float inp0 = tr ? tar[(size_t)b0 * 2 + e] : sc[0];
      float inp1 = tr ? tar[(size_t)(b0 + 1) * 2 + e] : sc[1];
      float yt0 = ctd0 + inp0 * wtM + wtb;
      float yt1 = ctd1 + inp1 * wtM + wtb;
      float gi, gf, gg, go;
      gate_combine(0, gi, gf, gg, go);
      gates_apply(0, gi, gf, gg, go, yt0);
      gate_combine(1, gi, gf, gg, go);
      gates_apply(1, gi, gf, gg, go, yt1);
    }
    __syncthreads();
    head_store(1 + e);
  }
}

extern "C" void kernel_launch(void* const* d_in, const int* in_sizes, int n_in,
                              void* d_out, int out_size, void* d_ws, size_t ws_size,
                              hipStream_t stream) {
  const float* E     = (const float*)d_in[0];
  const float* yin   = (const float*)d_in[1];
  const float* tar   = (const float*)d_in[2];
  const int*   train = (const int*)d_in[3];
  const float* Wd_w  = (const float*)d_in[4];
  const float* Wd_b  = (const float*)d_in[5];
  const float* Ud_w  = (const float*)d_in[6];
  const float* vd_w  = (const float*)d_in[7];
  const float* wt_w  = (const float*)d_in[8];
  const float* wt_b  = (const float*)d_in[9];
  const float* Wy_w  = (const float*)d_in[10];
  const float* Wy_b  = (const float*)d_in[11];
  const float* vy_w  = (const float*)d_in[12];
  const float* vy_b  = (const float*)d_in[13];
  const float* Wih   = (const float*)d_in[14];
  const float* Whh   = (const float*)d_in[15];
  const float* bih   = (const float*)d_in[16];
  const float* bhh   = (const float*)d_in[17];

  float* out = (float*)d_out;

  if (ws_size >= (size_t)WQ_BYTES) {
    u16* wq = (u16*)d_ws;
    prep_kernel<<<dim3(WQ_ELEMS / 256), dim3(256), 0, stream>>>(
        Wd_w, Whh, Wy_w, wq);
    scan_kernel<1><<<dim3(BB / NROW), dim3(NTH), 0, stream>>>(
        E, yin, tar, train, wq, Wd_b, Ud_w, vd_w, wt_w, wt_b,
        wq + WY16_OFF, Wy_b, vy_w, vy_b, Wih, wq, bih, bhh, out);
  } else {
    scan_kernel<0><<<dim3(BB / NROW), dim3(NTH), 0, stream>>>(
        E, yin, tar, train, Wd_w, Wd_b, Ud_w, vd_w, wt_w, wt_b,
        Wy_w, Wy_b, vy_w, vy_b, Wih, Whh, bih, bhh, out);
  }

  (void)in_sizes; (void)n_in; (void)out_size;
}

// Round 4
// 2809.760 us; speedup vs baseline: 1.2778x; 1.2778x over previous
//
#include <hip/hip_runtime.h>

// TemporalAttentionDecoder_three_step: B=512, T=64, M=P=256. in f32, out f32.
// R10: 1108us. VALU 49%, occ 48%, insensitive to occupancy/traffic/domains.
// R11: per-thread-contiguous weights -> destroyed coalescing (lanes 768B
//      apart, 64 lines per load) -> 3590us. REVERTED. (Its B2' softmax fold
//      passed correctness; kept.)
// R12 theory: 256 lockstep blocks read the SAME weight lines in the SAME
//      order each step -> L2 bank hotspot (32 CUs per XCD-L2 serialize on one
//      line) + VGPR=64 left loads unprefetched -> exposed latency x16/phase.
//      Fix: (1) block-rotated k-order, rot=(bid>>3)&15 (distinct within XCD);
//      (2) explicit double-buffered weight prefetch (6 H8 in flight);
//      (3) B2' fold: per-wave redundant softmax -> 4 barriers/step.
// f32 state: creg (j<256); f16: h,c,y1,E,ct,weights; dots accumulate f32.

typedef unsigned short u16;
typedef unsigned int u32;
typedef _Float16 half_t;
typedef half_t h2 __attribute__((ext_vector_type(2)));

#define BB 512
#define TT 64
#define MM 256
#define YS 264   // y1l row stride (u16); measured conflict-free (R6/R7)
#define ES 68    // e16T row stride (u16); 2-way (free)
#define NROW 2
#define NTH 1024

// ws layout (u16), all k-blocked n-major [kb][n][8]:
//   WdT8 [64kb][256n][8]  @ 0       (131072)
//   WhhT8[32kb][1024n][8] @ 131072  (262144)
//   WyT8 [64kb][256n][8]  @ 393216  (131072)
#define WD16_OFF  0
#define WHH16_OFF 131072
#define WY16_OFF  393216
#define WQ_ELEMS  524288
#define WQ_BYTES  (WQ_ELEMS * 2)

struct H8 { h2 p[4]; };   // 16B = 8 f16

#if defined(__has_builtin)
#if __has_builtin(__builtin_amdgcn_fdot2)
#define FDOT2(a, b, c) __builtin_amdgcn_fdot2((a), (b), (c), false)
#endif
#endif
#ifndef FDOT2
__device__ __forceinline__ float FDOT2(h2 a, h2 b, float c) {
  return c + (float)a[0] * (float)b[0] + (float)a[1] * (float)b[1];
}
#endif

__device__ __forceinline__ float dot8(const H8 w, const H8 a, float acc) {
  acc = FDOT2(w.p[0], a.p[0], acc);
  acc = FDOT2(w.p[1], a.p[1], acc);
  acc = FDOT2(w.p[2], a.p[2], acc);
  acc = FDOT2(w.p[3], a.p[3], acc);
  return acc;
}
__device__ __forceinline__ u16 f2h(float f) {
  union { half_t h; u16 u; } x; x.h = (half_t)f; return x.u;
}
__device__ __forceinline__ float h2f(u16 u) {
  union { u16 u; half_t h; } x; x.u = u; return (float)x.h;
}
__device__ __forceinline__ void unpackH8(const H8 v, float f[8]) {
#pragma unroll
  for (int i = 0; i < 8; ++i) f[i] = (float)v.p[i >> 1][i & 1];
}
__device__ __forceinline__ void ldf8(const float* p, float f[8]) {
  float4 a = *(const float4*)p;
  float4 b = *(const float4*)(p + 4);
  f[0]=a.x; f[1]=a.y; f[2]=a.z; f[3]=a.w;
  f[4]=b.x; f[5]=b.y; f[6]=b.z; f[7]=b.w;
}
__device__ __forceinline__ float tanh_fast(float x) {
  float e = __builtin_amdgcn_exp2f(x * 2.885390081777927f);
  return 1.0f - 2.0f * __builtin_amdgcn_rcpf(1.0f + e);
}
__device__ __forceinline__ float sigmoid_fast(float x) {
  float e = __builtin_amdgcn_exp2f(x * -1.4426950408889634f);
  return __builtin_amdgcn_rcpf(1.0f + e);
}

// ---- prep: f32 -> f16, k-blocked n-major ----
__global__ __launch_bounds__(256) void prep_kernel(
    const float* __restrict__ Wd, const float* __restrict__ Whh,
    const float* __restrict__ Wy, u16* __restrict__ o) {
  int i = blockIdx.x * 256 + threadIdx.x;   // 0..524287
  float v;
  if (i < WHH16_OFF) {
    int ki = i & 7, n = (i >> 3) & 255, kb = i >> 11;
    v = Wd[n * 512 + kb * 8 + ki];
  } else if (i < WY16_OFF) {
    int r = i - WHH16_OFF;
    int ki = r & 7, n = (r >> 3) & 1023, kb = r >> 13;
    v = Whh[n * 256 + kb * 8 + ki];
  } else {
    int r = i - WY16_OFF;
    int ki = r & 7, n = (r >> 3) & 255, kb = r >> 11;
    v = Wy[n * 512 + kb * 8 + ki];
  }
  o[i] = f2h(v);
}

template <int WQ>
__global__ __launch_bounds__(NTH, 4) void scan_kernel(
    const float* __restrict__ E,      // (B,T,M)
    const float* __restrict__ yin,    // (B,T,1)
    const float* __restrict__ tar,    // (B,2)
    const int*   __restrict__ train,  // (1)
    const void*  __restrict__ Wd_q,   // WQ1: WdT8 f16 | WQ0: f32 row-major
    const float* __restrict__ Wd_b,
    const float* __restrict__ Ud_w,   // (256,256) f32
    const float* __restrict__ vd_w,
    const float* __restrict__ wt_w,   // (257)
    const float* __restrict__ wt_b,
    const void*  __restrict__ Wy_q,
    const float* __restrict__ Wy_b,
    const float* __restrict__ vy_w,
    const float* __restrict__ vy_b,
    const float* __restrict__ Wih,    // (1024)
    const void*  __restrict__ Whh_q,
    const float* __restrict__ bih,
    const float* __restrict__ bhh,
    float* __restrict__ out)          // (3*B)
{
  __shared__ __align__(16) u16   y1l[NROW][TT * YS];   // 66KB f16 y1
  __shared__ __align__(16) u16   e16T[NROW][MM * ES];  // 68KB f16 E^T
  __shared__ __align__(16) u32   hs16[NROW][256];      // h pairs [0,128), c [128,256)
  __shared__ __align__(16) u32   ctx16p[NROW][128];    // ct f16 pairs
  __shared__ __align__(16) float px1[4][MM];   // x1: [0]=h r0+b, [1]=h r1+b, [2]=c r0, [3]=c r1
  __shared__ __align__(16) float pg[6][MM];    // grp1: i r0,i r1,f r0,f r1,g r0,g r1
  __shared__ __align__(16) float pg3[4][MM];   // o: grp2(r0,r1), grp3(r0,r1)
  __shared__ __align__(16) float lpart[NROW][8][TT];
  __shared__ __align__(16) u16   betas16[8][TT];       // per-wave beta copies
  __shared__ __align__(16) float ysh[NROW][TT];
  __shared__ float red[16];
  __shared__ float sc[NROW];

  const int j   = threadIdx.x;         // 0..1023
  const int n   = j & 255;             // output index
  const int grp = j >> 8;              // group 0..3 (wave-aligned: 4 waves each)
  const int wv  = j >> 6;              // wave 0..15
  const int b0  = blockIdx.x * NROW;   // batch rows b0, b0+1
  const int rot = (blockIdx.x >> 3) & 15;  // L2 decongestion rotation

  if (j < 512) ((u32*)hs16)[j] = 0;
  float creg0 = 0.f, creg1 = 0.f;      // live in grp0 threads

  // gate constants (consumed by grp0)
  const float wih0 = Wih[n],       wih1 = Wih[n + 256];
  const float wih2 = Wih[n + 512], wih3 = Wih[n + 768];
  const float bb0 = bih[n]       + bhh[n];
  const float bb1 = bih[n + 256] + bhh[n + 256];
  const float bb2 = bih[n + 512] + bhh[n + 512];
  const float bb3 = bih[n + 768] + bhh[n + 768];
  const float wtM = wt_w[MM], wtb = wt_b[0];

  // ---- stage yin rows ----
  if (j < NROW * TT)
    ysh[j >> 6][j & 63] = yin[(size_t)(b0 + (j >> 6)) * TT + (j & 63)];

  // ---- stage E^T (f16) into LDS for both rows ----
  {
    const float* __restrict__ Eb0 = E + (size_t)b0 * TT * MM;
    for (int i = j; i < NROW * TT * MM; i += NTH) {
      int r = i >> 14;
      int idx = i & 16383;
      int t = idx >> 8, m = idx & 255;
      e16T[r][m * ES + t] = f2h(Eb0[i]);
    }
  }

  // ---- y1 into LDS: thread (grp,n): row grp>>1, t-half grp&1, column n ----
  {
    const int rs = grp >> 1, ths = grp & 1;
    const float* __restrict__ Eb = E + (size_t)(b0 + rs) * TT * MM;
    const float* __restrict__ Uj = Ud_w + (size_t)n * MM;
    for (int t0 = ths * 32; t0 < ths * 32 + 32; t0 += 16) {
      float acc[16];
#pragma unroll
      for (int i = 0; i < 16; ++i) acc[i] = 0.f;
      for (int m0 = 0; m0 < MM; m0 += 8) {
        float w[8]; ldf8(Uj + m0, w);
#pragma unroll
        for (int tt = 0; tt < 16; ++tt) {
          float e[8]; ldf8(Eb + (size_t)(t0 + tt) * MM + m0, e);
#pragma unroll
          for (int mm = 0; mm < 8; ++mm) acc[tt] = fmaf(e[mm], w[mm], acc[tt]);
        }
      }
#pragma unroll
      for (int tt = 0; tt < 16; ++tt)
        y1l[rs][(t0 + tt) * YS + n] = f2h(acc[tt]);
    }
  }
  __syncthreads();

  // ---- gates: torch LSTMCell order i,f,g,o; grp0 threads, both rows ----
  auto gates_apply = [&](int r, float gi, float gf, float gg, float go,
                         float ytil) {
    gi += ytil * wih0 + bb0;
    gf += ytil * wih1 + bb1;
    gg += ytil * wih2 + bb2;
    go += ytil * wih3 + bb3;
    float& cr = r ? creg1 : creg0;
    float c = sigmoid_fast(gf) * cr + sigmoid_fast(gi) * tanh_fast(gg);
    float h = sigmoid_fast(go) * tanh_fast(c);
    cr = c;
    u16* hsu = (u16*)hs16[r];
    hsu[n] = f2h(h);
    hsu[256 + n] = f2h(c);
  };

  // ---- head: grp = (row<<1)|seg; seg0 = h-seg, seg1 = ct-seg ----
  auto head_store = [&](int outIdx) {
    float p = 0.f;
    const int rr = grp >> 1, seg = grp & 1;
    const u32* st = seg ? ctx16p[rr] : hs16[rr];
    if (WQ) {
      const u16* pw = (const u16*)Wy_q + ((size_t)(seg * 32) * 256 + n) * 8;
#pragma unroll 2
      for (int kb = 0; kb < 32; ++kb) {
        H8 w = *(const H8*)pw; pw += 2048;
        H8 s = *(const H8*)&st[kb * 4];
        p = dot8(w, s, p);
      }
    } else {
      const float* W = (const float*)Wy_q + (size_t)n * 512 + seg * 256;
#pragma unroll 2
      for (int kb = 0; kb < 32; ++kb) {
        H8 sv = *(const H8*)&st[kb * 4];
        float sf[8]; unpackH8(sv, sf);
        float w[8]; ldf8(W + kb * 8, w);
#pragma unroll
        for (int i = 0; i < 8; ++i) p = fmaf(sf[i], w[i], p);
      }
    }
    if (grp) px1[grp - 1][n] = p;   // px1 free; reuse as head parts
    __syncthreads();
    if (grp == 0) {
      float q0 = (p + px1[0][n] + Wy_b[n]) * vy_w[n];
      float q1 = (px1[1][n] + px1[2][n] + Wy_b[n]) * vy_w[n];
#pragma unroll
      for (int off = 32; off; off >>= 1) {
        q0 += __shfl_xor(q0, off, 64);
        q1 += __shfl_xor(q1, off, 64);
      }
      if ((j & 63) == 0) { red[wv] = q0; red[4 + wv] = q1; }
    }
    __syncthreads();
    if (j == 0) {
      float o0 = red[0] + red[1] + red[2] + red[3] + vy_b[0];
      float o1 = red[4] + red[5] + red[6] + red[7] + vy_b[0];
      out[(size_t)outIdx * BB + b0] = o0;
      out[(size_t)outIdx * BB + b0 + 1] = o1;
      sc[0] = o0; sc[1] = o1;
    }
    __syncthreads();
  };

  // ---- mv4: Whh@h both rows, same group split as stream (no Wd) ----
  auto mv4 = [&](float& m0, float& m1, float& m2, float& m3, float& m4,
                 float& m5) {
    m0 = m1 = m2 = m3 = m4 = m5 = 0.f;
    if (WQ) {
      const u16* Whh16 = (const u16*)Whh_q;
      if (grp < 2) {
        const int kb0 = grp << 4;
        const u16* pw = Whh16 + ((size_t)kb0 * 1024 + n) * 8;
#pragma unroll 2
        for (int kb2 = 0; kb2 < 16; ++kb2) {
          const int kb = kb0 + kb2;
          H8 h0 = *(const H8*)&hs16[0][kb * 4];
          H8 h1 = *(const H8*)&hs16[1][kb * 4];
          H8 w0 = *(const H8*)pw;
          H8 w1 = *(const H8*)(pw + 2048);
          H8 w2 = *(const H8*)(pw + 4096);
          pw += 8192;
          m0 = dot8(w0, h0, m0); m1 = dot8(w0, h1, m1);
          m2 = dot8(w1, h0, m2); m3 = dot8(w1, h1, m3);
          m4 = dot8(w2, h0, m4); m5 = dot8(w2, h1, m5);
        }
      } else {
        const int half = grp - 2;
        const u16* p3 = Whh16 + ((size_t)(half * 16) * 1024 + 768 + n) * 8;
#pragma unroll 2
        for (int kb2 = 0; kb2 < 16; ++kb2) {
          const int kg = half * 16 + kb2;
          H8 w3 = *(const H8*)p3; p3 += 8192;
          H8 h0 = *(const H8*)&hs16[0][kg * 4];
          H8 h1 = *(const H8*)&hs16[1][kg * 4];
          m0 = dot8(w3, h0, m0); m1 = dot8(w3, h1, m1);
        }
      }
    } else {
      const float* Whf = (const float*)Whh_q;
      if (grp < 2) {
        const int kb0 = grp << 4;
        const float* pw0 = Whf + (size_t)n * 256 + kb0 * 8;
        const float* pw1 = pw0 + 256 * 256;
        const float* pw2 = pw0 + 512 * 256;
#pragma unroll 2
        for (int kb2 = 0; kb2 < 16; ++kb2) {
          const int kb = kb0 + kb2;
          H8 h0v = *(const H8*)&hs16[0][kb * 4];
          H8 h1v = *(const H8*)&hs16[1][kb * 4];
          float hf0[8], hf1[8]; unpackH8(h0v, hf0); unpackH8(h1v, hf1);
          float w0[8], w1[8], w2[8];
          ldf8(pw0 + kb2 * 8, w0);
          ldf8(pw1 + kb2 * 8, w1);
          ldf8(pw2 + kb2 * 8, w2);
#pragma unroll
          for (int i = 0; i < 8; ++i) {
            m0 = fmaf(hf0[i], w0[i], m0); m1 = fmaf(hf1[i], w0[i], m1);
            m2 = fmaf(hf0[i], w1[i], m2); m3 = fmaf(hf1[i], w1[i], m3);
            m4 = fmaf(hf0[i], w2[i], m4); m5 = fmaf(hf1[i], w2[i], m5);
          }
        }
      } else {
        const int half = grp - 2;
        const float* p3f = Whf + ((size_t)(768 + n)) * 256 + half * 128;
#pragma unroll 2
        for (int kb2 = 0; kb2 < 16; ++kb2) {
          const int kg = half * 16 + kb2;
          H8 h0v = *(const H8*)&hs16[0][kg * 4];
          H8 h1v = *(const H8*)&hs16[1][kg * 4];
          float hf0[8], hf1[8]; unpackH8(h0v, hf0); unpackH8(h1v, hf1);
          float w3[8]; ldf8(p3f + kb2 * 8, w3);
#pragma unroll
          for (int i = 0; i < 8; ++i) {
            m0 = fmaf(hf0[i], w3[i], m0); m1 = fmaf(hf1[i], w3[i], m1);
          }
        }
      }
    }
  };

  // ================= scan over T steps =================
  for (int step = 0; step < TT; ++step) {
    // ---- stream: rotated k-order + double-buffered weight prefetch ----
    float s0 = 0.f, s1 = 0.f, s2 = 0.f, s3 = 0.f, s4 = 0.f, s5 = 0.f;
    {
      float a0 = 0, a1 = 0, a2 = 0, a3 = 0, a4 = 0, a5 = 0;
      if (WQ) {
        const u16* Whh16 = (const u16*)Whh_q;
        if (grp < 2) {
          // gates i,f,g; k-half kb0..kb0+15; both rows
          const int kb0 = grp << 4;
          const u16* __restrict__ wb = Whh16 + ((size_t)kb0 * 1024 + n) * 8;
          H8 wa0, wa1, wa2, wb0, wb1, wb2;
          {
            const u16* p = wb + (size_t)rot * 8192;
            wa0 = *(const H8*)p;
            wa1 = *(const H8*)(p + 2048);
            wa2 = *(const H8*)(p + 4096);
          }
#pragma unroll
          for (int kb2 = 0; kb2 < 16; kb2 += 2) {
            {
              const int kr = (kb2 + 1 + rot) & 15;
              const u16* p = wb + (size_t)kr * 8192;
              wb0 = *(const H8*)p;
              wb1 = *(const H8*)(p + 2048);
              wb2 = *(const H8*)(p + 4096);
            }
            {
              const int kb = kb0 + ((kb2 + rot) & 15);
              H8 h0 = *(const H8*)&hs16[0][kb * 4];
              H8 h1 = *(const H8*)&hs16[1][kb * 4];
              a0 = dot8(wa0, h0, a0); a1 = dot8(wa0, h1, a1);
              a2 = dot8(wa1, h0, a2); a3 = dot8(wa1, h1, a3);
              a4 = dot8(wa2, h0, a4); a5 = dot8(wa2, h1, a5);
            }
            if (kb2 < 14) {
              const int kr = (kb2 + 2 + rot) & 15;
              const u16* p = wb + (size_t)kr * 8192;
              wa0 = *(const H8*)p;
              wa1 = *(const H8*)(p + 2048);
              wa2 = *(const H8*)(p + 4096);
            }
            {
              const int kb = kb0 + ((kb2 + 1 + rot) & 15);
              H8 h0 = *(const H8*)&hs16[0][kb * 4];
              H8 h1 = *(const H8*)&hs16[1][kb * 4];
              a0 = dot8(wb0, h0, a0); a1 = dot8(wb0, h1, a1);
              a2 = dot8(wb1, h0, a2); a3 = dot8(wb1, h1, a3);
              a4 = dot8(wb2, h0, a4); a5 = dot8(wb2, h1, a5);
            }
          }
        } else {
          // Wd k-half (x1, both rows) + gate o k-half (both rows)
          const int half = grp - 2;
          const u16* __restrict__ pdb =
              (const u16*)Wd_q + ((size_t)(half * 32) * 256 + n) * 8;
          const u16* __restrict__ p3b =
              Whh16 + ((size_t)(half * 16) * 1024 + 768 + n) * 8;
          H8 da0, da1, da2, db0, db1, db2;   // wd0, wd1, w3
          {
            const u16* pd = pdb + (size_t)rot * 4096;
            da0 = *(const H8*)pd;
            da1 = *(const H8*)(pd + 2048);
            da2 = *(const H8*)(p3b + (size_t)rot * 8192);
          }
#pragma unroll
          for (int kb2 = 0; kb2 < 16; kb2 += 2) {
            {
              const int kr = (kb2 + 1 + rot) & 15;
              const u16* pd = pdb + (size_t)kr * 4096;
              db0 = *(const H8*)pd;
              db1 = *(const H8*)(pd + 2048);
              db2 = *(const H8*)(p3b + (size_t)kr * 8192);
            }
            {
              const int kr = (kb2 + rot) & 15;
              const int kd = half * 32 + kr * 2;
              const int kg = half * 16 + kr;
              H8 s00 = *(const H8*)&hs16[0][kd * 4];
              H8 s01 = *(const H8*)&hs16[0][kd * 4 + 4];
              H8 s10 = *(const H8*)&hs16[1][kd * 4];
              H8 s11 = *(const H8*)&hs16[1][kd * 4 + 4];
              H8 h0 = *(const H8*)&hs16[0][kg * 4];
              H8 h1 = *(const H8*)&hs16[1][kg * 4];
              a0 = dot8(da0, s00, a0); a0 = dot8(da1, s01, a0);
              a1 = dot8(da0, s10, a1); a1 = dot8(da1, s11, a1);
              a2 = dot8(da2, h0, a2);  a3 = dot8(da2, h1, a3);
            }
            if (kb2 < 14) {
              const int kr = (kb2 + 2 + rot) & 15;
              const u16* pd = pdb + (size_t)kr * 4096;
              da0 = *(const H8*)pd;
              da1 = *(const H8*)(pd + 2048);
              da2 = *(const H8*)(p3b + (size_t)kr * 8192);
            }
            {
              const int kr = (kb2 + 1 + rot) & 15;
              const int kd = half * 32 + kr * 2;
              const int kg = half * 16 + kr;
              H8 s00 = *(const H8*)&hs16[0][kd * 4];
              H8 s01 = *(const H8*)&hs16[0][kd * 4 + 4];
              H8 s10 = *(const H8*)&hs16[1][kd * 4];
              H8 s11 = *(const H8*)&hs16[1][kd * 4 + 4];
              H8 h0 = *(const H8*)&hs16[0][kg * 4];
              H8 h1 = *(const H8*)&hs16[1][kg * 4];
              a0 = dot8(db0, s00, a0); a0 = dot8(db1, s01, a0);
              a1 = dot8(db0, s10, a1); a1 = dot8(db1, s11, a1);
              a2 = dot8(db2, h0, a2);  a3 = dot8(db2, h1, a3);
            }
          }
        }
      } else {
        const float* Whf = (const float*)Whh_q;
        if (grp < 2) {
          const int kb0 = grp << 4;
          const float* pw0 = Whf + (size_t)n * 256 + kb0 * 8;
          const float* pw1 = pw0 + 256 * 256;
          const float* pw2 = pw0 + 512 * 256;
#pragma unroll 2
          for (int kb2 = 0; kb2 < 16; ++kb2) {
            const int kb = kb0 + kb2;
            H8 h0v = *(const H8*)&hs16[0][kb * 4];
            H8 h1v = *(const H8*)&hs16[1][kb * 4];
            float hf0[8], hf1[8]; unpackH8(h0v, hf0); unpackH8(h1v, hf1);
            float w0[8], w1[8], w2[8];
            ldf8(pw0 + kb2 * 8, w0);
            ldf8(pw1 + kb2 * 8, w1);
            ldf8(pw2 + kb2 * 8, w2);
#pragma unroll
            for (int i = 0; i < 8; ++i) {
              a0 = fmaf(hf0[i], w0[i], a0); a1 = fmaf(hf1[i], w0[i], a1);
              a2 = fmaf(hf0[i], w1[i], a2); a3 = fmaf(hf1[i], w1[i], a3);
              a4 = fmaf(hf0[i], w2[i], a4); a5 = fmaf(hf1[i], w2[i], a5);
            }
          }
        } else {
          const int half = grp - 2;
          const float* Wdf = (const float*)Wd_q + (size_t)n * 512 + half * 256;
          const float* p3f = Whf + ((size_t)(768 + n)) * 256 + half * 128;
#pragma unroll 2
          for (int kb2 = 0; kb2 < 16; ++kb2) {
            const int kd = half * 32 + kb2 * 2;
            const int kg = half * 16 + kb2;
            H8 s00v = *(const H8*)&hs16[0][kd * 4];
            H8 s01v = *(const H8*)&hs16[0][kd * 4 + 4];
            H8 s10v = *(const H8*)&hs16[1][kd * 4];
            H8 s11v = *(const H8*)&hs16[1][kd * 4 + 4];
            float f00[8], f01[8], f10[8], f11[8];
            unpackH8(s00v, f00); unpackH8(s01v, f01);
            unpackH8(s10v, f10); unpackH8(s11v, f11);
            H8 h0v = *(const H8*)&hs16[0][kg * 4];
            H8 h1v = *(const H8*)&hs16[1][kg * 4];
            float hf0[8], hf1[8]; unpackH8(h0v, hf0); unpackH8(h1v, hf1);
            float wd0[8], wd1[8], w3[8];
            ldf8(Wdf + kb2 * 16, wd0);
            ldf8(Wdf + kb2 * 16 + 8, wd1);
            ldf8(p3f + kb2 * 8, w3);
#pragma unroll
            for (int i = 0; i < 8; ++i) {
              a0 = fmaf(f00[i], wd0[i], a0); a0 = fmaf(f01[i], wd1[i], a0);
              a1 = fmaf(f10[i], wd0[i], a1); a1 = fmaf(f11[i], wd1[i], a1);
              a2 = fmaf(hf0[i], w3[i], a2);  a3 = fmaf(hf1[i], w3[i], a3);
            }
          }
        }
      }
      if (grp == 0) {
        s0 = a0; s1 = a1; s2 = a2; s3 = a3; s4 = a4; s5 = a5;
      } else if (grp == 1) {
        pg[0][n] = a0; pg[1][n] = a1; pg[2][n] = a2;
        pg[3][n] = a3; pg[4][n] = a4; pg[5][n] = a5;
      } else if (grp == 2) {
        float bia = Wd_b[n];
        px1[0][n] = a0 + bia; px1[1][n] = a1 + bia;
        pg3[0][n] = a2; pg3[1][n] = a3;
      } else {
        px1[2][n] = a0; px1[3][n] = a1;
        pg3[2][n] = a2; pg3[3][n] = a3;
      }
    }
    __syncthreads();

    // ---- B1: l[t] eighth-partials; thread = (r, e8, t); 32 m each ----
    {
      const int r = j >> 9, e8 = (j >> 6) & 7, t = j & 63;
      const u16* __restrict__ yrow = &y1l[r][t * YS + e8 * 32];
      const float* __restrict__ xh = &px1[r][e8 * 32];
      const float* __restrict__ xc = &px1[2 + r][e8 * 32];
      const float* __restrict__ vp = vd_w + e8 * 32;
      float lp = 0.f;
#pragma unroll
      for (int m0 = 0; m0 < 32; m0 += 8) {
        H8 yv = *(const H8*)(yrow + m0);
        float yf[8]; unpackH8(yv, yf);
        float xf[8]; ldf8(xh + m0, xf);
        float xg[8]; ldf8(xc + m0, xg);
        float vf[8]; ldf8(vp + m0, vf);
#pragma unroll
        for (int mm = 0; mm < 8; ++mm) {
          float z = tanh_fast(xf[mm] + xg[mm] + yf[mm]);
          lp = fmaf(z, vf[mm], lp);
        }
      }
      lpart[r][e8][t] = lp;
    }
    __syncthreads();

    // ---- B2': per-wave redundant softmax + ct + ytil reduce (j<512) ----
    if (j < 512) {
      const int r = j >> 8, lane = j & 63;
      float l = lpart[r][0][lane] + lpart[r][1][lane] + lpart[r][2][lane] +
                lpart[r][3][lane] + lpart[r][4][lane] + lpart[r][5][lane] +
                lpart[r][6][lane] + lpart[r][7][lane];
      float mx = l;
#pragma unroll
      for (int off = 32; off; off >>= 1) mx = fmaxf(mx, __shfl_xor(mx, off, 64));
      float e = __builtin_amdgcn_exp2f((l - mx) * 1.4426950408889634f);
      float sm = e;
#pragma unroll
      for (int off = 32; off; off >>= 1) sm += __shfl_xor(sm, off, 64);
      betas16[wv][lane] = f2h(e * __builtin_amdgcn_rcpf(sm));
      asm volatile("s_waitcnt lgkmcnt(0)" ::: "memory");
      const u16* __restrict__ bp = betas16[wv];
      const u16* __restrict__ ep = &e16T[r][n * ES];
      float acc = 0.f;
#pragma unroll
      for (int t0 = 0; t0 < TT; t0 += 8) {
        H8 bv = *(const H8*)(bp + t0);
        h2 e0 = *(const h2*)(ep + t0);
        h2 e1 = *(const h2*)(ep + t0 + 2);
        h2 e2 = *(const h2*)(ep + t0 + 4);
        h2 e3 = *(const h2*)(ep + t0 + 6);
        acc = FDOT2(bv.p[0], e0, acc);
        acc = FDOT2(bv.p[1], e1, acc);
        acc = FDOT2(bv.p[2], e2, acc);
        acc = FDOT2(bv.p[3], e3, acc);
      }
      ((u16*)ctx16p[r])[n] = f2h(acc);
      float p = acc * wt_w[n];
#pragma unroll
      for (int off = 32; off; off >>= 1) p += __shfl_xor(p, off, 64);
      if ((j & 63) == 0) red[wv] = p;   // wv 0..3 -> r0, 4..7 -> r1
    }
    __syncthreads();

    // ---- G: combine partials + gates (grp0, both rows) ----
    if (grp == 0) {
      float yt0 = red[0] + red[1] + red[2] + red[3] + ysh[0][step] * wtM + wtb;
      float yt1 = red[4] + red[5] + red[6] + red[7] + ysh[1][step] * wtM + wtb;
      gates_apply(0, s0 + pg[0][n], s2 + pg[2][n], s4 + pg[4][n],
                  pg3[0][n] + pg3[2][n], yt0);
      gates_apply(1, s1 + pg[1][n], s3 + pg[3][n], s5 + pg[5][n],
                  pg3[1][n] + pg3[3][n], yt1);
    }
    __syncthreads();
  }

  // ================= finals =================
  // ctdot from final f16 ct (same precision path as head)
  if (j < 512) {
    const int r = j >> 8;
    float p = h2f(((const u16*)ctx16p[r])[n]) * wt_w[n];
#pragma unroll
    for (int off = 32; off; off >>= 1) p += __shfl_xor(p, off, 64);
    if ((j & 63) == 0) red[wv] = p;
  }
  __syncthreads();
  const float ctd0 = red[0] + red[1] + red[2] + red[3];
  const float ctd1 = red[4] + red[5] + red[6] + red[7];

  head_store(0);  // y_Tp1 (sc[] holds it for train==0 feedback)

  const int tr = train[0];
  for (int e = 0; e < 2; ++e) {
    float m0, m1, m2, m3, m4, m5;
    mv4(m0, m1, m2, m3, m4, m5);
    if (grp == 1) {
      pg[0][n] = m0; pg[1][n] = m1; pg[2][n] = m2;
      pg[3][n] = m3; pg[4][n] = m4; pg[5][n] = m5;
    } else if (grp == 2) {
      pg3[0][n] = m0; pg3[1][n] = m1;
    } else if (grp == 3) {
      pg3[2][n] = m0; pg3[3][n] = m1;
    }
    __syncthreads();
    if (grp == 0) {
      float inp0 = tr ? tar[(size_t)b0 * 2 + e] : sc[0];
      float inp1 = tr ? tar[(size_t)(b0 + 1) * 2 + e] : sc[1];
      float yt0 = ctd0 + inp0 * wtM + wtb;
      float yt1 = ctd1 + inp1 * wtM + wtb;
      gates_apply(0, m0 + pg[0][n], m2 + pg[2][n], m4 + pg[4][n],
                  pg3[0][n] + pg3[2][n], yt0);
      gates_apply(1, m1 + pg[1][n], m3 + pg[3][n], m5 + pg[5][n],
                  pg3[1][n] + pg3[3][n], yt1);
    }
    __syncthreads();
    head_store(1 + e);
  }
}

extern "C" void kernel_launch(void* const* d_in, const int* in_sizes, int n_in,
                              void* d_out, int out_size, void* d_ws, size_t ws_size,
                              hipStream_t stream) {
  const float* E     = (const float*)d_in[0];
  const float* yin   = (const float*)d_in[1];
  const float* tar   = (const float*)d_in[2];
  const int*   train = (const int*)d_in[3];
  const float* Wd_w  = (const float*)d_in[4];
  const float* Wd_b  = (const float*)d_in[5];
  const float* Ud_w  = (const float*)d_in[6];
  const float* vd_w  = (const float*)d_in[7];
  const float* wt_w  = (const float*)d_in[8];
  const float* wt_b  = (const float*)d_in[9];
  const float* Wy_w  = (const float*)d_in[10];
  const float* Wy_b  = (const float*)d_in[11];
  const float* vy_w  = (const float*)d_in[12];
  const float* vy_b  = (const float*)d_in[13];
  const float* Wih   = (const float*)d_in[14];
  const float* Whh   = (const float*)d_in[15];
  const float* bih   = (const float*)d_in[16];
  const float* bhh   = (const float*)d_in[17];

  float* out = (float*)d_out;

  if (ws_size >= (size_t)WQ_BYTES) {
    u16* wq = (u16*)d_ws;
    prep_kernel<<<dim3(WQ_ELEMS / 256), dim3(256), 0, stream>>>(
        Wd_w, Whh, Wy_w, wq);
    scan_kernel<1><<<dim3(BB / NROW), dim3(NTH), 0, stream>>>(
        E, yin, tar, train, wq + WD16_OFF, Wd_b, Ud_w, vd_w, wt_w, wt_b,
        wq + WY16_OFF, Wy_b, vy_w, vy_b, Wih, wq + WHH16_OFF, bih, bhh, out);
  } else {
    scan_kernel<0><<<dim3(BB / NROW), dim3(NTH), 0, stream>>>(
        E, yin, tar, train, Wd_w, Wd_b, Ud_w, vd_w, wt_w, wt_b,
        Wy_w, Wy_b, vy_w, vy_b, Wih, Whh, bih, bhh, out);
  }

  (void)in_sizes; (void)n_in; (void)out_size;
}

// Round 5
// 2207.196 us; speedup vs baseline: 1.6267x; 1.2730x over previous
//
#include <hip/hip_runtime.h>

// TemporalAttentionDecoder_three_step: B=512, T=64, M=P=256. in f32, out f32.
// R10: 1087us. VALU 49%, occ 48%. Step ~15.6us = S(5.7 L2-stream) + B1(4) +
//      B2'(1.5) + G + barrier/latency ramps (sum of phase floors).
// R12: prefetch + rotation REGRESSED to 2810us -- NOT the prefetch's fault:
//      launch_bounds(1024,4) let compiler target 8 waves/EU (VGPR<=64,
//      impossible: LDS caps 1 blk/CU) -> spilled prefetch regs to scratch
//      (FETCH 3.5GB, WRITE 226MB). Occupancy bug, theory untested.
// R13: R10 + amdgpu_waves_per_eu(4,4) (pin 16 waves/CU, unlock VGPR<=128,
//      forbid the spill-for-occupancy heuristic) + 2-deep weight prefetch in
//      stream phase (no rotation). Fills post-barrier latency hole of the
//      768KB/step L2 stream. Keep B2' softmax fold (4 barriers/step).
// f32 state: creg (grp0); f16: h,c,y1,E,ct,weights; dots accumulate f32.

typedef unsigned short u16;
typedef unsigned int u32;
typedef _Float16 half_t;
typedef half_t h2 __attribute__((ext_vector_type(2)));

#define BB 512
#define TT 64
#define MM 256
#define YS 264   // y1l row stride (u16); measured conflict-free (R6/R7)
#define ES 68    // e16T row stride (u16); 2-way (free)
#define NROW 2
#define NTH 1024

// ws layout (u16), all k-blocked n-major [kb][n][8]:
//   WdT8 [64kb][256n][8]  @ 0       (131072)
//   WhhT8[32kb][1024n][8] @ 131072  (262144)
//   WyT8 [64kb][256n][8]  @ 393216  (131072)
#define WD16_OFF  0
#define WHH16_OFF 131072
#define WY16_OFF  393216
#define WQ_ELEMS  524288
#define WQ_BYTES  (WQ_ELEMS * 2)

struct H8 { h2 p[4]; };   // 16B = 8 f16

#if defined(__has_builtin)
#if __has_builtin(__builtin_amdgcn_fdot2)
#define FDOT2(a, b, c) __builtin_amdgcn_fdot2((a), (b), (c), false)
#endif
#endif
#ifndef FDOT2
__device__ __forceinline__ float FDOT2(h2 a, h2 b, float c) {
  return c + (float)a[0] * (float)b[0] + (float)a[1] * (float)b[1];
}
#endif

__device__ __forceinline__ float dot8(const H8 w, const H8 a, float acc) {
  acc = FDOT2(w.p[0], a.p[0], acc);
  acc = FDOT2(w.p[1], a.p[1], acc);
  acc = FDOT2(w.p[2], a.p[2], acc);
  acc = FDOT2(w.p[3], a.p[3], acc);
  return acc;
}
__device__ __forceinline__ u16 f2h(float f) {
  union { half_t h; u16 u; } x; x.h = (half_t)f; return x.u;
}
__device__ __forceinline__ float h2f(u16 u) {
  union { u16 u; half_t h; } x; x.u = u; return (float)x.h;
}
__device__ __forceinline__ void unpackH8(const H8 v, float f[8]) {
#pragma unroll
  for (int i = 0; i < 8; ++i) f[i] = (float)v.p[i >> 1][i & 1];
}
__device__ __forceinline__ void ldf8(const float* p, float f[8]) {
  float4 a = *(const float4*)p;
  float4 b = *(const float4*)(p + 4);
  f[0]=a.x; f[1]=a.y; f[2]=a.z; f[3]=a.w;
  f[4]=b.x; f[5]=b.y; f[6]=b.z; f[7]=b.w;
}
__device__ __forceinline__ float tanh_fast(float x) {
  float e = __builtin_amdgcn_exp2f(x * 2.885390081777927f);
  return 1.0f - 2.0f * __builtin_amdgcn_rcpf(1.0f + e);
}
__device__ __forceinline__ float sigmoid_fast(float x) {
  float e = __builtin_amdgcn_exp2f(x * -1.4426950408889634f);
  return __builtin_amdgcn_rcpf(1.0f + e);
}

// ---- prep: f32 -> f16, k-blocked n-major ----
__global__ __launch_bounds__(256) void prep_kernel(
    const float* __restrict__ Wd, const float* __restrict__ Whh,
    const float* __restrict__ Wy, u16* __restrict__ o) {
  int i = blockIdx.x * 256 + threadIdx.x;   // 0..524287
  float v;
  if (i < WHH16_OFF) {
    int ki = i & 7, n = (i >> 3) & 255, kb = i >> 11;
    v = Wd[n * 512 + kb * 8 + ki];
  } else if (i < WY16_OFF) {
    int r = i - WHH16_OFF;
    int ki = r & 7, n = (r >> 3) & 1023, kb = r >> 13;
    v = Whh[n * 256 + kb * 8 + ki];
  } else {
    int r = i - WY16_OFF;
    int ki = r & 7, n = (r >> 3) & 255, kb = r >> 11;
    v = Wy[n * 512 + kb * 8 + ki];
  }
  o[i] = f2h(v);
}

template <int WQ>
__global__ __launch_bounds__(NTH)
__attribute__((amdgpu_waves_per_eu(4, 4)))
void scan_kernel(
    const float* __restrict__ E,      // (B,T,M)
    const float* __restrict__ yin,    // (B,T,1)
    const float* __restrict__ tar,    // (B,2)
    const int*   __restrict__ train,  // (1)
    const void*  __restrict__ Wd_q,   // WQ1: WdT8 f16 | WQ0: f32 row-major
    const float* __restrict__ Wd_b,
    const float* __restrict__ Ud_w,   // (256,256) f32
    const float* __restrict__ vd_w,
    const float* __restrict__ wt_w,   // (257)
    const float* __restrict__ wt_b,
    const void*  __restrict__ Wy_q,
    const float* __restrict__ Wy_b,
    const float* __restrict__ vy_w,
    const float* __restrict__ vy_b,
    const float* __restrict__ Wih,    // (1024)
    const void*  __restrict__ Whh_q,
    const float* __restrict__ bih,
    const float* __restrict__ bhh,
    float* __restrict__ out)          // (3*B)
{
  __shared__ __align__(16) u16   y1l[NROW][TT * YS];   // 66KB f16 y1
  __shared__ __align__(16) u16   e16T[NROW][MM * ES];  // 68KB f16 E^T
  __shared__ __align__(16) u32   hs16[NROW][256];      // h pairs [0,128), c [128,256)
  __shared__ __align__(16) u32   ctx16p[NROW][128];    // ct f16 pairs
  __shared__ __align__(16) float px1[4][MM];   // x1: [0]=h r0+b, [1]=h r1+b, [2]=c r0, [3]=c r1
  __shared__ __align__(16) float pg[6][MM];    // grp1: i r0,i r1,f r0,f r1,g r0,g r1
  __shared__ __align__(16) float pg3[4][MM];   // o: grp2(r0,r1), grp3(r0,r1)
  __shared__ __align__(16) float lpart[NROW][8][TT];
  __shared__ __align__(16) u16   betas16[8][TT];       // per-wave beta copies
  __shared__ __align__(16) float ysh[NROW][TT];
  __shared__ float red[16];
  __shared__ float sc[NROW];

  const int j   = threadIdx.x;         // 0..1023
  const int n   = j & 255;             // output index
  const int grp = j >> 8;              // group 0..3 (wave-aligned: 4 waves each)
  const int wv  = j >> 6;              // wave 0..15
  const int b0  = blockIdx.x * NROW;   // batch rows b0, b0+1

  if (j < 512) ((u32*)hs16)[j] = 0;
  float creg0 = 0.f, creg1 = 0.f;      // live in grp0 threads

  // gate constants (consumed by grp0)
  const float wih0 = Wih[n],       wih1 = Wih[n + 256];
  const float wih2 = Wih[n + 512], wih3 = Wih[n + 768];
  const float bb0 = bih[n]       + bhh[n];
  const float bb1 = bih[n + 256] + bhh[n + 256];
  const float bb2 = bih[n + 512] + bhh[n + 512];
  const float bb3 = bih[n + 768] + bhh[n + 768];
  const float wtM = wt_w[MM], wtb = wt_b[0];

  // ---- stage yin rows ----
  if (j < NROW * TT)
    ysh[j >> 6][j & 63] = yin[(size_t)(b0 + (j >> 6)) * TT + (j & 63)];

  // ---- stage E^T (f16) into LDS for both rows ----
  {
    const float* __restrict__ Eb0 = E + (size_t)b0 * TT * MM;
    for (int i = j; i < NROW * TT * MM; i += NTH) {
      int r = i >> 14;
      int idx = i & 16383;
      int t = idx >> 8, m = idx & 255;
      e16T[r][m * ES + t] = f2h(Eb0[i]);
    }
  }

  // ---- y1 into LDS: thread (grp,n): row grp>>1, t-half grp&1, column n ----
  {
    const int rs = grp >> 1, ths = grp & 1;
    const float* __restrict__ Eb = E + (size_t)(b0 + rs) * TT * MM;
    const float* __restrict__ Uj = Ud_w + (size_t)n * MM;
    for (int t0 = ths * 32; t0 < ths * 32 + 32; t0 += 16) {
      float acc[16];
#pragma unroll
      for (int i = 0; i < 16; ++i) acc[i] = 0.f;
      for (int m0 = 0; m0 < MM; m0 += 8) {
        float w[8]; ldf8(Uj + m0, w);
#pragma unroll
        for (int tt = 0; tt < 16; ++tt) {
          float e[8]; ldf8(Eb + (size_t)(t0 + tt) * MM + m0, e);
#pragma unroll
          for (int mm = 0; mm < 8; ++mm) acc[tt] = fmaf(e[mm], w[mm], acc[tt]);
        }
      }
#pragma unroll
      for (int tt = 0; tt < 16; ++tt)
        y1l[rs][(t0 + tt) * YS + n] = f2h(acc[tt]);
    }
  }
  __syncthreads();

  // ---- gates: torch LSTMCell order i,f,g,o; grp0 threads, both rows ----
  auto gates_apply = [&](int r, float gi, float gf, float gg, float go,
                         float ytil) {
    gi += ytil * wih0 + bb0;
    gf += ytil * wih1 + bb1;
    gg += ytil * wih2 + bb2;
    go += ytil * wih3 + bb3;
    float& cr = r ? creg1 : creg0;
    float c = sigmoid_fast(gf) * cr + sigmoid_fast(gi) * tanh_fast(gg);
    float h = sigmoid_fast(go) * tanh_fast(c);
    cr = c;
    u16* hsu = (u16*)hs16[r];
    hsu[n] = f2h(h);
    hsu[256 + n] = f2h(c);
  };

  // ---- head: grp = (row<<1)|seg; seg0 = h-seg, seg1 = ct-seg ----
  auto head_store = [&](int outIdx) {
    float p = 0.f;
    const int rr = grp >> 1, seg = grp & 1;
    const u32* st = seg ? ctx16p[rr] : hs16[rr];
    if (WQ) {
      const u16* pw = (const u16*)Wy_q + ((size_t)(seg * 32) * 256 + n) * 8;
#pragma unroll 2
      for (int kb = 0; kb < 32; ++kb) {
        H8 w = *(const H8*)pw; pw += 2048;
        H8 s = *(const H8*)&st[kb * 4];
        p = dot8(w, s, p);
      }
    } else {
      const float* W = (const float*)Wy_q + (size_t)n * 512 + seg * 256;
#pragma unroll 2
      for (int kb = 0; kb < 32; ++kb) {
        H8 sv = *(const H8*)&st[kb * 4];
        float sf[8]; unpackH8(sv, sf);
        float w[8]; ldf8(W + kb * 8, w);
#pragma unroll
        for (int i = 0; i < 8; ++i) p = fmaf(sf[i], w[i], p);
      }
    }
    if (grp) px1[grp - 1][n] = p;   // px1 free; reuse as head parts
    __syncthreads();
    if (grp == 0) {
      float q0 = (p + px1[0][n] + Wy_b[n]) * vy_w[n];
      float q1 = (px1[1][n] + px1[2][n] + Wy_b[n]) * vy_w[n];
#pragma unroll
      for (int off = 32; off; off >>= 1) {
        q0 += __shfl_xor(q0, off, 64);
        q1 += __shfl_xor(q1, off, 64);
      }
      if ((j & 63) == 0) { red[wv] = q0; red[4 + wv] = q1; }
    }
    __syncthreads();
    if (j == 0) {
      float o0 = red[0] + red[1] + red[2] + red[3] + vy_b[0];
      float o1 = red[4] + red[5] + red[6] + red[7] + vy_b[0];
      out[(size_t)outIdx * BB + b0] = o0;
      out[(size_t)outIdx * BB + b0 + 1] = o1;
      sc[0] = o0; sc[1] = o1;
    }
    __syncthreads();
  };

  // ---- mv4: Whh@h both rows, same group split as stream (no Wd) ----
  auto mv4 = [&](float& m0, float& m1, float& m2, float& m3, float& m4,
                 float& m5) {
    m0 = m1 = m2 = m3 = m4 = m5 = 0.f;
    if (WQ) {
      const u16* Whh16 = (const u16*)Whh_q;
      if (grp < 2) {
        const int kb0 = grp << 4;
        const u16* pw = Whh16 + ((size_t)kb0 * 1024 + n) * 8;
#pragma unroll 2
        for (int kb2 = 0; kb2 < 16; ++kb2) {
          const int kb = kb0 + kb2;
          H8 h0 = *(const H8*)&hs16[0][kb * 4];
          H8 h1 = *(const H8*)&hs16[1][kb * 4];
          H8 w0 = *(const H8*)pw;
          H8 w1 = *(const H8*)(pw + 2048);
          H8 w2 = *(const H8*)(pw + 4096);
          pw += 8192;
          m0 = dot8(w0, h0, m0); m1 = dot8(w0, h1, m1);
          m2 = dot8(w1, h0, m2); m3 = dot8(w1, h1, m3);
          m4 = dot8(w2, h0, m4); m5 = dot8(w2, h1, m5);
        }
      } else {
        const int half = grp - 2;
        const u16* p3 = Whh16 + ((size_t)(half * 16) * 1024 + 768 + n) * 8;
#pragma unroll 2
        for (int kb2 = 0; kb2 < 16; ++kb2) {
          const int kg = half * 16 + kb2;
          H8 w3 = *(const H8*)p3; p3 += 8192;
          H8 h0 = *(const H8*)&hs16[0][kg * 4];
          H8 h1 = *(const H8*)&hs16[1][kg * 4];
          m0 = dot8(w3, h0, m0); m1 = dot8(w3, h1, m1);
        }
      }
    } else {
      const float* Whf = (const float*)Whh_q;
      if (grp < 2) {
        const int kb0 = grp << 4;
        const float* pw0 = Whf + (size_t)n * 256 + kb0 * 8;
        const float* pw1 = pw0 + 256 * 256;
        const float* pw2 = pw0 + 512 * 256;
#pragma unroll 2
        for (int kb2 = 0; kb2 < 16; ++kb2) {
          const int kb = kb0 + kb2;
          H8 h0v = *(const H8*)&hs16[0][kb * 4];
          H8 h1v = *(const H8*)&hs16[1][kb * 4];
          float hf0[8], hf1[8]; unpackH8(h0v, hf0); unpackH8(h1v, hf1);
          float w0[8], w1[8], w2[8];
          ldf8(pw0 + kb2 * 8, w0);
          ldf8(pw1 + kb2 * 8, w1);
          ldf8(pw2 + kb2 * 8, w2);
#pragma unroll
          for (int i = 0; i < 8; ++i) {
            m0 = fmaf(hf0[i], w0[i], m0); m1 = fmaf(hf1[i], w0[i], m1);
            m2 = fmaf(hf0[i], w1[i], m2); m3 = fmaf(hf1[i], w1[i], m3);
            m4 = fmaf(hf0[i], w2[i], m4); m5 = fmaf(hf1[i], w2[i], m5);
          }
        }
      } else {
        const int half = grp - 2;
        const float* p3f = Whf + ((size_t)(768 + n)) * 256 + half * 128;
#pragma unroll 2
        for (int kb2 = 0; kb2 < 16; ++kb2) {
          const int kg = half * 16 + kb2;
          H8 h0v = *(const H8*)&hs16[0][kg * 4];
          H8 h1v = *(const H8*)&hs16[1][kg * 4];
          float hf0[8], hf1[8]; unpackH8(h0v, hf0); unpackH8(h1v, hf1);
          float w3[8]; ldf8(p3f + kb2 * 8, w3);
#pragma unroll
          for (int i = 0; i < 8; ++i) {
            m0 = fmaf(hf0[i], w3[i], m0); m1 = fmaf(hf1[i], w3[i], m1);
          }
        }
      }
    }
  };

  // ================= scan over T steps =================
  for (int step = 0; step < TT; ++step) {
    // ---- stream: 2-deep weight prefetch (linear k-order) ----
    float s0 = 0.f, s1 = 0.f, s2 = 0.f, s3 = 0.f, s4 = 0.f, s5 = 0.f;
    {
      float a0 = 0, a1 = 0, a2 = 0, a3 = 0, a4 = 0, a5 = 0;
      if (WQ) {
        const u16* Whh16 = (const u16*)Whh_q;
        if (grp < 2) {
          // gates i,f,g; k-half kb0..kb0+15; both rows
          const int kb0 = grp << 4;
          const u16* __restrict__ wb = Whh16 + ((size_t)kb0 * 1024 + n) * 8;
          H8 wa0, wa1, wa2, wb0, wb1, wb2;
          wa0 = *(const H8*)wb;
          wa1 = *(const H8*)(wb + 2048);
          wa2 = *(const H8*)(wb + 4096);
#pragma unroll
          for (int kb2 = 0; kb2 < 16; kb2 += 2) {
            {
              const u16* p = wb + (size_t)(kb2 + 1) * 8192;
              wb0 = *(const H8*)p;
              wb1 = *(const H8*)(p + 2048);
              wb2 = *(const H8*)(p + 4096);
            }
            {
              const int kb = kb0 + kb2;
              H8 h0 = *(const H8*)&hs16[0][kb * 4];
              H8 h1 = *(const H8*)&hs16[1][kb * 4];
              a0 = dot8(wa0, h0, a0); a1 = dot8(wa0, h1, a1);
              a2 = dot8(wa1, h0, a2); a3 = dot8(wa1, h1, a3);
              a4 = dot8(wa2, h0, a4); a5 = dot8(wa2, h1, a5);
            }
            if (kb2 < 14) {
              const u16* p = wb + (size_t)(kb2 + 2) * 8192;
              wa0 = *(const H8*)p;
              wa1 = *(const H8*)(p + 2048);
              wa2 = *(const H8*)(p + 4096);
            }
            {
              const int kb = kb0 + kb2 + 1;
              H8 h0 = *(const H8*)&hs16[0][kb * 4];
              H8 h1 = *(const H8*)&hs16[1][kb * 4];
              a0 = dot8(wb0, h0, a0); a1 = dot8(wb0, h1, a1);
              a2 = dot8(wb1, h0, a2); a3 = dot8(wb1, h1, a3);
              a4 = dot8(wb2, h0, a4); a5 = dot8(wb2, h1, a5);
            }
          }
        } else {
          // Wd k-half (x1, both rows) + gate o k-half (both rows)
          const int half = grp - 2;
          const u16* __restrict__ pdb =
              (const u16*)Wd_q + ((size_t)(half * 32) * 256 + n) * 8;
          const u16* __restrict__ p3b =
              Whh16 + ((size_t)(half * 16) * 1024 + 768 + n) * 8;
          H8 da0, da1, da2, db0, db1, db2;   // wd0, wd1, w3
          da0 = *(const H8*)pdb;
          da1 = *(const H8*)(pdb + 2048);
          da2 = *(const H8*)p3b;
#pragma unroll
          for (int kb2 = 0; kb2 < 16; kb2 += 2) {
            {
              const u16* pd = pdb + (size_t)(kb2 + 1) * 4096;
              db0 = *(const H8*)pd;
              db1 = *(const H8*)(pd + 2048);
              db2 = *(const H8*)(p3b + (size_t)(kb2 + 1) * 8192);
            }
            {
              const int kd = half * 32 + kb2 * 2;
              const int kg = half * 16 + kb2;
              H8 s00 = *(const H8*)&hs16[0][kd * 4];
              H8 s01 = *(const H8*)&hs16[0][kd * 4 + 4];
              H8 s10 = *(const H8*)&hs16[1][kd * 4];
              H8 s11 = *(const H8*)&hs16[1][kd * 4 + 4];
              H8 h0 = *(const H8*)&hs16[0][kg * 4];
              H8 h1 = *(const H8*)&hs16[1][kg * 4];
              a0 = dot8(da0, s00, a0); a0 = dot8(da1, s01, a0);
              a1 = dot8(da0, s10, a1); a1 = dot8(da1, s11, a1);
              a2 = dot8(da2, h0, a2);  a3 = dot8(da2, h1, a3);
            }
            if (kb2 < 14) {
              const u16* pd = pdb + (size_t)(kb2 + 2) * 4096;
              da0 = *(const H8*)pd;
              da1 = *(const H8*)(pd + 2048);
              da2 = *(const H8*)(p3b + (size_t)(kb2 + 2) * 8192);
            }
            {
              const int kd = half * 32 + (kb2 + 1) * 2;
              const int kg = half * 16 + kb2 + 1;
              H8 s00 = *(const H8*)&hs16[0][kd * 4];
              H8 s01 = *(const H8*)&hs16[0][kd * 4 + 4];
              H8 s10 = *(const H8*)&hs16[1][kd * 4];
              H8 s11 = *(const H8*)&hs16[1][kd * 4 + 4];
              H8 h0 = *(const H8*)&hs16[0][kg * 4];
              H8 h1 = *(const H8*)&hs16[1][kg * 4];
              a0 = dot8(db0, s00, a0); a0 = dot8(db1, s01, a0);
              a1 = dot8(db0, s10, a1); a1 = dot8(db1, s11, a1);
              a2 = dot8(db2, h0, a2);  a3 = dot8(db2, h1, a3);
            }
          }
        }
      } else {
        const float* Whf = (const float*)Whh_q;
        if (grp < 2) {
          const int kb0 = grp << 4;
          const float* pw0 = Whf + (size_t)n * 256 + kb0 * 8;
          const float* pw1 = pw0 + 256 * 256;
          const float* pw2 = pw0 + 512 * 256;
#pragma unroll 2
          for (int kb2 = 0; kb2 < 16; ++kb2) {
            const int kb = kb0 + kb2;
            H8 h0v = *(const H8*)&hs16[0][kb * 4];
            H8 h1v = *(const H8*)&hs16[1][kb * 4];
            float hf0[8], hf1[8]; unpackH8(h0v, hf0); unpackH8(h1v, hf1);
            float w0[8], w1[8], w2[8];
            ldf8(pw0 + kb2 * 8, w0);
            ldf8(pw1 + kb2 * 8, w1);
            ldf8(pw2 + kb2 * 8, w2);
#pragma unroll
            for (int i = 0; i < 8; ++i) {
              a0 = fmaf(hf0[i], w0[i], a0); a1 = fmaf(hf1[i], w0[i], a1);
              a2 = fmaf(hf0[i], w1[i], a2); a3 = fmaf(hf1[i], w1[i], a3);
              a4 = fmaf(hf0[i], w2[i], a4); a5 = fmaf(hf1[i], w2[i], a5);
            }
          }
        } else {
          const int half = grp - 2;
          const float* Wdf = (const float*)Wd_q + (size_t)n * 512 + half * 256;
          const float* p3f = Whf + ((size_t)(768 + n)) * 256 + half * 128;
#pragma unroll 2
          for (int kb2 = 0; kb2 < 16; ++kb2) {
            const int kd = half * 32 + kb2 * 2;
            const int kg = half * 16 + kb2;
            H8 s00v = *(const H8*)&hs16[0][kd * 4];
            H8 s01v = *(const H8*)&hs16[0][kd * 4 + 4];
            H8 s10v = *(const H8*)&hs16[1][kd * 4];
            H8 s11v = *(const H8*)&hs16[1][kd * 4 + 4];
            float f00[8], f01[8], f10[8], f11[8];
            unpackH8(s00v, f00); unpackH8(s01v, f01);
            unpackH8(s10v, f10); unpackH8(s11v, f11);
            H8 h0v = *(const H8*)&hs16[0][kg * 4];
            H8 h1v = *(const H8*)&hs16[1][kg * 4];
            float hf0[8], hf1[8]; unpackH8(h0v, hf0); unpackH8(h1v, hf1);
            float wd0[8], wd1[8], w3[8];
            ldf8(Wdf + kb2 * 16, wd0);
            ldf8(Wdf + kb2 * 16 + 8, wd1);
            ldf8(p3f + kb2 * 8, w3);
#pragma unroll
            for (int i = 0; i < 8; ++i) {
              a0 = fmaf(f00[i], wd0[i], a0); a0 = fmaf(f01[i], wd1[i], a0);
              a1 = fmaf(f10[i], wd0[i], a1); a1 = fmaf(f11[i], wd1[i], a1);
              a2 = fmaf(hf0[i], w3[i], a2);  a3 = fmaf(hf1[i], w3[i], a3);
            }
          }
        }
      }
      if (grp == 0) {
        s0 = a0; s1 = a1; s2 = a2; s3 = a3; s4 = a4; s5 = a5;
      } else if (grp == 1) {
        pg[0][n] = a0; pg[1][n] = a1; pg[2][n] = a2;
        pg[3][n] = a3; pg[4][n] = a4; pg[5][n] = a5;
      } else if (grp == 2) {
        float bia = Wd_b[n];
        px1[0][n] = a0 + bia; px1[1][n] = a1 + bia;
        pg3[0][n] = a2; pg3[1][n] = a3;
      } else {
        px1[2][n] = a0; px1[3][n] = a1;
        pg3[2][n] = a2; pg3[3][n] = a3;
      }
    }
    __syncthreads();

    // ---- B1: l[t] eighth-partials; thread = (r, e8, t); 32 m each ----
    {
      const int r = j >> 9, e8 = (j >> 6) & 7, t = j & 63;
      const u16* __restrict__ yrow = &y1l[r][t * YS + e8 * 32];
      const float* __restrict__ xh = &px1[r][e8 * 32];
      const float* __restrict__ xc = &px1[2 + r][e8 * 32];
      const float* __restrict__ vp = vd_w + e8 * 32;
      float lp = 0.f;
#pragma unroll
      for (int m0 = 0; m0 < 32; m0 += 8) {
        H8 yv = *(const H8*)(yrow + m0);
        float yf[8]; unpackH8(yv, yf);
        float xf[8]; ldf8(xh + m0, xf);
        float xg[8]; ldf8(xc + m0, xg);
        float vf[8]; ldf8(vp + m0, vf);
#pragma unroll
        for (int mm = 0; mm < 8; ++mm) {
          float z = tanh_fast(xf[mm] + xg[mm] + yf[mm]);
          lp = fmaf(z, vf[mm], lp);
        }
      }
      lpart[r][e8][t] = lp;
    }
    __syncthreads();

    // ---- B2': per-wave redundant softmax + ct + ytil reduce (j<512) ----
    if (j < 512) {
      const int r = j >> 8, lane = j & 63;
      float l = lpart[r][0][lane] + lpart[r][1][lane] + lpart[r][2][lane] +
                lpart[r][3][lane] + lpart[r][4][lane] + lpart[r][5][lane] +
                lpart[r][6][lane] + lpart[r][7][lane];
      float mx = l;
#pragma unroll
      for (int off = 32; off; off >>= 1) mx = fmaxf(mx, __shfl_xor(mx, off, 64));
      float e = __builtin_amdgcn_exp2f((l - mx) * 1.4426950408889634f);
      float sm = e;
#pragma unroll
      for (int off = 32; off; off >>= 1) sm += __shfl_xor(sm, off, 64);
      betas16[wv][lane] = f2h(e * __builtin_amdgcn_rcpf(sm));
      asm volatile("s_waitcnt lgkmcnt(0)" ::: "memory");
      const u16* __restrict__ bp = betas16[wv];
      const u16* __restrict__ ep = &e16T[r][n * ES];
      float acc = 0.f;
#pragma unroll
      for (int t0 = 0; t0 < TT; t0 += 8) {
        H8 bv = *(const H8*)(bp + t0);
        h2 e0 = *(const h2*)(ep + t0);
        h2 e1 = *(const h2*)(ep + t0 + 2);
        h2 e2 = *(const h2*)(ep + t0 + 4);
        h2 e3 = *(const h2*)(ep + t0 + 6);
        acc = FDOT2(bv.p[0], e0, acc);
        acc = FDOT2(bv.p[1], e1, acc);
        acc = FDOT2(bv.p[2], e2, acc);
        acc = FDOT2(bv.p[3], e3, acc);
      }
      ((u16*)ctx16p[r])[n] = f2h(acc);
      float p = acc * wt_w[n];
#pragma unroll
      for (int off = 32; off; off >>= 1) p += __shfl_xor(p, off, 64);
      if ((j & 63) == 0) red[wv] = p;   // wv 0..3 -> r0, 4..7 -> r1
    }
    __syncthreads();

    // ---- G: combine partials + gates (grp0, both rows) ----
    if (grp == 0) {
      float yt0 = red[0] + red[1] + red[2] + red[3] + ysh[0][step] * wtM + wtb;
      float yt1 = red[4] + red[5] + red[6] + red[7] + ysh[1][step] * wtM + wtb;
      gates_apply(0, s0 + pg[0][n], s2 + pg[2][n], s4 + pg[4][n],
                  pg3[0][n] + pg3[2][n], yt0);
      gates_apply(1, s1 + pg[1][n], s3 + pg[3][n], s5 + pg[5][n],
                  pg3[1][n] + pg3[3][n], yt1);
    }
    __syncthreads();
  }

  // ================= finals =================
  // ctdot from final f16 ct (same precision path as head)
  if (j < 512) {
    const int r = j >> 8;
    float p = h2f(((const u16*)ctx16p[r])[n]) * wt_w[n];
#pragma unroll
    for (int off = 32; off; off >>= 1) p += __shfl_xor(p, off, 64);
    if ((j & 63) == 0) red[wv] = p;
  }
  __syncthreads();
  const float ctd0 = red[0] + red[1] + red[2] + red[3];
  const float ctd1 = red[4] + red[5] + red[6] + red[7];

  head_store(0);  // y_Tp1 (sc[] holds it for train==0 feedback)

  const int tr = train[0];
  for (int e = 0; e < 2; ++e) {
    float m0, m1, m2, m3, m4, m5;
    mv4(m0, m1, m2, m3, m4, m5);
    if (grp == 1) {
      pg[0][n] = m0; pg[1][n] = m1; pg[2][n] = m2;
      pg[3][n] = m3; pg[4][n] = m4; pg[5][n] = m5;
    } else if (grp == 2) {
      pg3[0][n] = m0; pg3[1][n] = m1;
    } else if (grp == 3) {
      pg3[2][n] = m0; pg3[3][n] = m1;
    }
    __syncthreads();
    if (grp == 0) {
      float inp0 = tr ? tar[(size_t)b0 * 2 + e] : sc[0];
      float inp1 = tr ? tar[(size_t)(b0 + 1) * 2 + e] : sc[1];
      float yt0 = ctd0 + inp0 * wtM + wtb;
      float yt1 = ctd1 + inp1 * wtM + wtb;
      gates_apply(0, m0 + pg[0][n], m2 + pg[2][n], m4 + pg[4][n],
                  pg3[0][n] + pg3[2][n], yt0);
      gates_apply(1, m1 + pg[1][n], m3 + pg[3][n], m5 + pg[5][n],
                  pg3[1][n] + pg3[3][n], yt1);
    }
    __syncthreads();
    head_store(1 + e);
  }
}

extern "C" void kernel_launch(void* const* d_in, const int* in_sizes, int n_in,
                              void* d_out, int out_size, void* d_ws, size_t ws_size,
                              hipStream_t stream) {
  const float* E     = (const float*)d_in[0];
  const float* yin   = (const float*)d_in[1];
  const float* tar   = (const float*)d_in[2];
  const int*   train = (const int*)d_in[3];
  const float* Wd_w  = (const float*)d_in[4];
  const float* Wd_b  = (const float*)d_in[5];
  const float* Ud_w  = (const float*)d_in[6];
  const float* vd_w  = (const float*)d_in[7];
  const float* wt_w  = (const float*)d_in[8];
  const float* wt_b  = (const float*)d_in[9];
  const float* Wy_w  = (const float*)d_in[10];
  const float* Wy_b  = (const float*)d_in[11];
  const float* vy_w  = (const float*)d_in[12];
  const float* vy_b  = (const float*)d_in[13];
  const float* Wih   = (const float*)d_in[14];
  const float* Whh   = (const float*)d_in[15];
  const float* bih   = (const float*)d_in[16];
  const float* bhh   = (const float*)d_in[17];

  float* out = (float*)d_out;

  if (ws_size >= (size_t)WQ_BYTES) {
    u16* wq = (u16*)d_ws;
    prep_kernel<<<dim3(WQ_ELEMS / 256), dim3(256), 0, stream>>>(
        Wd_w, Whh, Wy_w, wq);
    scan_kernel<1><<<dim3(BB / NROW), dim3(NTH), 0, stream>>>(
        E, yin, tar, train, wq + WD16_OFF, Wd_b, Ud_w, vd_w, wt_w, wt_b,
        wq + WY16_OFF, Wy_b, vy_w, vy_b, Wih, wq + WHH16_OFF, bih, bhh, out);
  } else {
    scan_kernel<0><<<dim3(BB / NROW), dim3(NTH), 0, stream>>>(
        E, yin, tar, train, Wd_w, Wd_b, Ud_w, vd_w, wt_w, wt_b,
        Wy_w, Wy_b, vy_w, vy_b, Wih, Whh, bih, bhh, out);
  }

  (void)in_sizes; (void)n_in; (void)out_size;
}

// Round 6
// 1078.077 us; speedup vs baseline: 3.3304x; 2.0473x over previous
//
#include <hip/hip_runtime.h>

// TemporalAttentionDecoder_three_step: B=512, T=64, M=P=256. in f32, out f32.
// R10: 1087us. VALU 49%, occ 48%; insensitive to occupancy/traffic/domains ->
//      homogeneous waves stall in lockstep (all stream, then all B1).
// R12/R13: register prefetch spilled BOTH times: at wg=1024 the allocator
//      pins VGPR=64 regardless of launch_bounds/waves_per_eu -> any extra
//      live state goes to scratch (FETCH 3+GB). 64 VGPR = hard wall here.
// R14: wave specialization, zero extra registers. Only Wd(x1, 256KB) is
//      needed at B1; Whh(512KB, 2/3 of stream) is needed only at G. Step:
//      S1 (all waves: x1 4-way split-k) | bar |
//      B1(waves 0-7, 64m/thr) PARALLEL S2(waves 8-15: Whh all-gates both
//      rows -> f16 pgs) -- S2's L2 latency hides under B1's VALU | bar |
//      B2' (waves 0-7: per-wave softmax + ct) | bar | G (j<256) | bar.
//      4 barriers/step, same traffic, same coalesced layouts.
// f32 state: creg (j<256); f16: h,c,y1,E,ct,weights,gate-partials.

typedef unsigned short u16;
typedef unsigned int u32;
typedef _Float16 half_t;
typedef half_t h2 __attribute__((ext_vector_type(2)));

#define BB 512
#define TT 64
#define MM 256
#define YS 264   // y1l row stride (u16); measured conflict-free (R6/R7)
#define ES 68    // e16T row stride (u16); 2-way (free)
#define NROW 2
#define NTH 1024

// ws layout (u16), all k-blocked n-major [kb][n][8]:
//   WdT8 [64kb][256n][8]  @ 0       (131072)
//   WhhT8[32kb][1024n][8] @ 131072  (262144)
//   WyT8 [64kb][256n][8]  @ 393216  (131072)
#define WD16_OFF  0
#define WHH16_OFF 131072
#define WY16_OFF  393216
#define WQ_ELEMS  524288
#define WQ_BYTES  (WQ_ELEMS * 2)

struct H8 { h2 p[4]; };   // 16B = 8 f16

#if defined(__has_builtin)
#if __has_builtin(__builtin_amdgcn_fdot2)
#define FDOT2(a, b, c) __builtin_amdgcn_fdot2((a), (b), (c), false)
#endif
#endif
#ifndef FDOT2
__device__ __forceinline__ float FDOT2(h2 a, h2 b, float c) {
  return c + (float)a[0] * (float)b[0] + (float)a[1] * (float)b[1];
}
#endif

__device__ __forceinline__ float dot8(const H8 w, const H8 a, float acc) {
  acc = FDOT2(w.p[0], a.p[0], acc);
  acc = FDOT2(w.p[1], a.p[1], acc);
  acc = FDOT2(w.p[2], a.p[2], acc);
  acc = FDOT2(w.p[3], a.p[3], acc);
  return acc;
}
__device__ __forceinline__ u16 f2h(float f) {
  union { half_t h; u16 u; } x; x.h = (half_t)f; return x.u;
}
__device__ __forceinline__ float h2f(u16 u) {
  union { u16 u; half_t h; } x; x.u = u; return (float)x.h;
}
__device__ __forceinline__ void unpackH8(const H8 v, float f[8]) {
#pragma unroll
  for (int i = 0; i < 8; ++i) f[i] = (float)v.p[i >> 1][i & 1];
}
__device__ __forceinline__ void ldf8(const float* p, float f[8]) {
  float4 a = *(const float4*)p;
  float4 b = *(const float4*)(p + 4);
  f[0]=a.x; f[1]=a.y; f[2]=a.z; f[3]=a.w;
  f[4]=b.x; f[5]=b.y; f[6]=b.z; f[7]=b.w;
}
__device__ __forceinline__ float tanh_fast(float x) {
  float e = __builtin_amdgcn_exp2f(x * 2.885390081777927f);
  return 1.0f - 2.0f * __builtin_amdgcn_rcpf(1.0f + e);
}
__device__ __forceinline__ float sigmoid_fast(float x) {
  float e = __builtin_amdgcn_exp2f(x * -1.4426950408889634f);
  return __builtin_amdgcn_rcpf(1.0f + e);
}

// ---- prep: f32 -> f16, k-blocked n-major ----
__global__ __launch_bounds__(256) void prep_kernel(
    const float* __restrict__ Wd, const float* __restrict__ Whh,
    const float* __restrict__ Wy, u16* __restrict__ o) {
  int i = blockIdx.x * 256 + threadIdx.x;   // 0..524287
  float v;
  if (i < WHH16_OFF) {
    int ki = i & 7, n = (i >> 3) & 255, kb = i >> 11;
    v = Wd[n * 512 + kb * 8 + ki];
  } else if (i < WY16_OFF) {
    int r = i - WHH16_OFF;
    int ki = r & 7, n = (r >> 3) & 1023, kb = r >> 13;
    v = Whh[n * 256 + kb * 8 + ki];
  } else {
    int r = i - WY16_OFF;
    int ki = r & 7, n = (r >> 3) & 255, kb = r >> 11;
    v = Wy[n * 512 + kb * 8 + ki];
  }
  o[i] = f2h(v);
}

template <int WQ>
__global__ __launch_bounds__(NTH, 4) void scan_kernel(
    const float* __restrict__ E,      // (B,T,M)
    const float* __restrict__ yin,    // (B,T,1)
    const float* __restrict__ tar,    // (B,2)
    const int*   __restrict__ train,  // (1)
    const void*  __restrict__ Wd_q,   // WQ1: WdT8 f16 | WQ0: f32 row-major
    const float* __restrict__ Wd_b,
    const float* __restrict__ Ud_w,   // (256,256) f32
    const float* __restrict__ vd_w,
    const float* __restrict__ wt_w,   // (257)
    const float* __restrict__ wt_b,
    const void*  __restrict__ Wy_q,
    const float* __restrict__ Wy_b,
    const float* __restrict__ vy_w,
    const float* __restrict__ vy_b,
    const float* __restrict__ Wih,    // (1024)
    const void*  __restrict__ Whh_q,
    const float* __restrict__ bih,
    const float* __restrict__ bhh,
    float* __restrict__ out)          // (3*B)
{
  __shared__ __align__(16) u16   y1l[NROW][TT * YS];   // 66KB f16 y1
  __shared__ __align__(16) u16   e16T[NROW][MM * ES];  // 68KB f16 E^T
  __shared__ __align__(16) u32   hs16[NROW][256];      // h pairs [0,128), c [128,256)
  __shared__ __align__(16) u32   ctx16p[NROW][128];    // ct f16 pairs
  __shared__ __align__(16) float px1[8][MM];   // x1 quarters [(r<<2)|q]; head reuse
  __shared__ __align__(16) u16   pgs[16][MM];  // gate partials [(g<<2)|(half<<1)|r]
  __shared__ __align__(16) float lpart[NROW][4][TT];
  __shared__ __align__(16) u16   betas16[8][TT];       // per-wave beta copies
  __shared__ __align__(16) float ysh[NROW][TT];
  __shared__ float red[16];
  __shared__ float sc[NROW];

  const int j   = threadIdx.x;         // 0..1023
  const int n   = j & 255;             // output index
  const int grp = j >> 8;              // group 0..3 (wave-aligned)
  const int wv  = j >> 6;              // wave 0..15
  const int b0  = blockIdx.x * NROW;   // batch rows b0, b0+1

  if (j < 512) ((u32*)hs16)[j] = 0;
  float creg0 = 0.f, creg1 = 0.f;      // live in j<256 threads

  // gate constants (consumed by j<256)
  const float wih0 = Wih[n],       wih1 = Wih[n + 256];
  const float wih2 = Wih[n + 512], wih3 = Wih[n + 768];
  const float bb0 = bih[n]       + bhh[n];
  const float bb1 = bih[n + 256] + bhh[n + 256];
  const float bb2 = bih[n + 512] + bhh[n + 512];
  const float bb3 = bih[n + 768] + bhh[n + 768];
  const float wtM = wt_w[MM], wtb = wt_b[0];

  // ---- stage yin rows ----
  if (j < NROW * TT)
    ysh[j >> 6][j & 63] = yin[(size_t)(b0 + (j >> 6)) * TT + (j & 63)];

  // ---- stage E^T (f16) into LDS for both rows ----
  {
    const float* __restrict__ Eb0 = E + (size_t)b0 * TT * MM;
    for (int i = j; i < NROW * TT * MM; i += NTH) {
      int r = i >> 14;
      int idx = i & 16383;
      int t = idx >> 8, m = idx & 255;
      e16T[r][m * ES + t] = f2h(Eb0[i]);
    }
  }

  // ---- y1 into LDS: thread (grp,n): row grp>>1, t-half grp&1, column n ----
  {
    const int rs = grp >> 1, ths = grp & 1;
    const float* __restrict__ Eb = E + (size_t)(b0 + rs) * TT * MM;
    const float* __restrict__ Uj = Ud_w + (size_t)n * MM;
    for (int t0 = ths * 32; t0 < ths * 32 + 32; t0 += 16) {
      float acc[16];
#pragma unroll
      for (int i = 0; i < 16; ++i) acc[i] = 0.f;
      for (int m0 = 0; m0 < MM; m0 += 8) {
        float w[8]; ldf8(Uj + m0, w);
#pragma unroll
        for (int tt = 0; tt < 16; ++tt) {
          float e[8]; ldf8(Eb + (size_t)(t0 + tt) * MM + m0, e);
#pragma unroll
          for (int mm = 0; mm < 8; ++mm) acc[tt] = fmaf(e[mm], w[mm], acc[tt]);
        }
      }
#pragma unroll
      for (int tt = 0; tt < 16; ++tt)
        y1l[rs][(t0 + tt) * YS + n] = f2h(acc[tt]);
    }
  }
  __syncthreads();

  // ---- gates: torch LSTMCell order i,f,g,o; j<256 threads, both rows ----
  auto gates_apply = [&](int r, float gi, float gf, float gg, float go,
                         float ytil) {
    gi += ytil * wih0 + bb0;
    gf += ytil * wih1 + bb1;
    gg += ytil * wih2 + bb2;
    go += ytil * wih3 + bb3;
    float& cr = r ? creg1 : creg0;
    float c = sigmoid_fast(gf) * cr + sigmoid_fast(gi) * tanh_fast(gg);
    float h = sigmoid_fast(go) * tanh_fast(c);
    cr = c;
    u16* hsu = (u16*)hs16[r];
    hsu[n] = f2h(h);
    hsu[256 + n] = f2h(c);
  };

  // ---- S2: Whh@h all 4 gates x both rows; waves 8-15 only ----
  auto whh_gates = [&]() {
    if (wv >= 8) {
      const int jj = j - 512;
      const int n2 = jj & 255, half = jj >> 8;   // k-half
      float a00 = 0, a01 = 0, a10 = 0, a11 = 0;
      float a20 = 0, a21 = 0, a30 = 0, a31 = 0;
      if (WQ) {
        const u16* __restrict__ base =
            (const u16*)Whh_q + ((size_t)(half * 16) * 1024 + n2) * 8;
#pragma unroll 2
        for (int i = 0; i < 16; ++i) {
          const u16* p = base + (size_t)i * 8192;
          H8 w0 = *(const H8*)p;
          H8 w1 = *(const H8*)(p + 2048);
          H8 w2 = *(const H8*)(p + 4096);
          H8 w3 = *(const H8*)(p + 6144);
          const int kb = half * 16 + i;
          H8 h0v = *(const H8*)&hs16[0][kb * 4];
          H8 h1v = *(const H8*)&hs16[1][kb * 4];
          a00 = dot8(w0, h0v, a00); a01 = dot8(w0, h1v, a01);
          a10 = dot8(w1, h0v, a10); a11 = dot8(w1, h1v, a11);
          a20 = dot8(w2, h0v, a20); a21 = dot8(w2, h1v, a21);
          a30 = dot8(w3, h0v, a30); a31 = dot8(w3, h1v, a31);
        }
      } else {
        const float* __restrict__ base =
            (const float*)Whh_q + (size_t)n2 * 256 + half * 128;
#pragma unroll 2
        for (int i = 0; i < 16; ++i) {
          const int kb = half * 16 + i;
          H8 h0v = *(const H8*)&hs16[0][kb * 4];
          H8 h1v = *(const H8*)&hs16[1][kb * 4];
          float hf0[8], hf1[8]; unpackH8(h0v, hf0); unpackH8(h1v, hf1);
          float w0[8], w1[8], w2[8], w3[8];
          ldf8(base + i * 8, w0);
          ldf8(base + 256 * 256 + i * 8, w1);
          ldf8(base + 512 * 256 + i * 8, w2);
          ldf8(base + 768 * 256 + i * 8, w3);
#pragma unroll
          for (int m = 0; m < 8; ++m) {
            a00 = fmaf(hf0[m], w0[m], a00); a01 = fmaf(hf1[m], w0[m], a01);
            a10 = fmaf(hf0[m], w1[m], a10); a11 = fmaf(hf1[m], w1[m], a11);
            a20 = fmaf(hf0[m], w2[m], a20); a21 = fmaf(hf1[m], w2[m], a21);
            a30 = fmaf(hf0[m], w3[m], a30); a31 = fmaf(hf1[m], w3[m], a31);
          }
        }
      }
      const int hb = half << 1;
      pgs[(0 << 2) | hb | 0][n2] = f2h(a00);
      pgs[(0 << 2) | hb | 1][n2] = f2h(a01);
      pgs[(1 << 2) | hb | 0][n2] = f2h(a10);
      pgs[(1 << 2) | hb | 1][n2] = f2h(a11);
      pgs[(2 << 2) | hb | 0][n2] = f2h(a20);
      pgs[(2 << 2) | hb | 1][n2] = f2h(a21);
      pgs[(3 << 2) | hb | 0][n2] = f2h(a30);
      pgs[(3 << 2) | hb | 1][n2] = f2h(a31);
    }
  };

  // ---- G: combine pgs halves + LSTM gates (j<256, both rows) ----
  auto gates_combine_apply = [&](float yt0, float yt1) {
    float gi0 = h2f(pgs[0][n]) + h2f(pgs[2][n]);
    float gf0 = h2f(pgs[4][n]) + h2f(pgs[6][n]);
    float gg0 = h2f(pgs[8][n]) + h2f(pgs[10][n]);
    float go0 = h2f(pgs[12][n]) + h2f(pgs[14][n]);
    gates_apply(0, gi0, gf0, gg0, go0, yt0);
    float gi1 = h2f(pgs[1][n]) + h2f(pgs[3][n]);
    float gf1 = h2f(pgs[5][n]) + h2f(pgs[7][n]);
    float gg1 = h2f(pgs[9][n]) + h2f(pgs[11][n]);
    float go1 = h2f(pgs[13][n]) + h2f(pgs[15][n]);
    gates_apply(1, gi1, gf1, gg1, go1, yt1);
  };

  // ---- head: grp = (row<<1)|seg; seg0 = h-seg, seg1 = ct-seg ----
  auto head_store = [&](int outIdx) {
    float p = 0.f;
    const int rr = grp >> 1, seg = grp & 1;
    const u32* st = seg ? ctx16p[rr] : hs16[rr];
    if (WQ) {
      const u16* pw = (const u16*)Wy_q + ((size_t)(seg * 32) * 256 + n) * 8;
#pragma unroll 2
      for (int kb = 0; kb < 32; ++kb) {
        H8 w = *(const H8*)pw; pw += 2048;
        H8 s = *(const H8*)&st[kb * 4];
        p = dot8(w, s, p);
      }
    } else {
      const float* W = (const float*)Wy_q + (size_t)n * 512 + seg * 256;
#pragma unroll 2
      for (int kb = 0; kb < 32; ++kb) {
        H8 sv = *(const H8*)&st[kb * 4];
        float sf[8]; unpackH8(sv, sf);
        float w[8]; ldf8(W + kb * 8, w);
#pragma unroll
        for (int i = 0; i < 8; ++i) p = fmaf(sf[i], w[i], p);
      }
    }
    if (grp) px1[grp - 1][n] = p;   // px1 free after scan; reuse as head parts
    __syncthreads();
    if (grp == 0) {
      float q0 = (p + px1[0][n] + Wy_b[n]) * vy_w[n];
      float q1 = (px1[1][n] + px1[2][n] + Wy_b[n]) * vy_w[n];
#pragma unroll
      for (int off = 32; off; off >>= 1) {
        q0 += __shfl_xor(q0, off, 64);
        q1 += __shfl_xor(q1, off, 64);
      }
      if ((j & 63) == 0) { red[wv] = q0; red[4 + wv] = q1; }
    }
    __syncthreads();
    if (j == 0) {
      float o0 = red[0] + red[1] + red[2] + red[3] + vy_b[0];
      float o1 = red[4] + red[5] + red[6] + red[7] + vy_b[0];
      out[(size_t)outIdx * BB + b0] = o0;
      out[(size_t)outIdx * BB + b0 + 1] = o1;
      sc[0] = o0; sc[1] = o1;
    }
    __syncthreads();
  };

  // ================= scan over T steps =================
  for (int step = 0; step < TT; ++step) {
    // ---- S1: x1 = Wd.[h|c], 4-way split-k (all waves) ----
    {
      float ax0 = 0.f, ax1 = 0.f;
      if (WQ) {
        const u16* pd = (const u16*)Wd_q + ((size_t)(grp * 16) * 256 + n) * 8;
#pragma unroll 4
        for (int i = 0; i < 16; ++i) {
          H8 w = *(const H8*)pd; pd += 2048;
          const int kb = grp * 16 + i;
          H8 s0 = *(const H8*)&hs16[0][kb * 4];
          H8 s1 = *(const H8*)&hs16[1][kb * 4];
          ax0 = dot8(w, s0, ax0);
          ax1 = dot8(w, s1, ax1);
        }
      } else {
        const float* pd = (const float*)Wd_q + (size_t)n * 512 + grp * 128;
#pragma unroll 2
        for (int i = 0; i < 16; ++i) {
          const int kb = grp * 16 + i;
          H8 s0v = *(const H8*)&hs16[0][kb * 4];
          H8 s1v = *(const H8*)&hs16[1][kb * 4];
          float f0[8], f1[8]; unpackH8(s0v, f0); unpackH8(s1v, f1);
          float w[8]; ldf8(pd + i * 8, w);
#pragma unroll
          for (int m = 0; m < 8; ++m) {
            ax0 = fmaf(f0[m], w[m], ax0);
            ax1 = fmaf(f1[m], w[m], ax1);
          }
        }
      }
      if (grp == 0) { float b = Wd_b[n]; ax0 += b; ax1 += b; }
      px1[grp][n] = ax0;
      px1[4 + grp][n] = ax1;
    }
    __syncthreads();

    // ---- B1 (waves 0-7) PARALLEL S2 (waves 8-15) ----
    if (wv < 8) {
      const int r = j >> 8, e4 = (j >> 6) & 3, t = j & 63;
      const int mb = e4 * 64;
      const u16* __restrict__ yrow = &y1l[r][t * YS + mb];
      const float* __restrict__ p0 = &px1[(r << 2) | 0][mb];
      const float* __restrict__ p1 = &px1[(r << 2) | 1][mb];
      const float* __restrict__ p2 = &px1[(r << 2) | 2][mb];
      const float* __restrict__ p3 = &px1[(r << 2) | 3][mb];
      const float* __restrict__ vp = vd_w + mb;
      float lp = 0.f;
#pragma unroll 2
      for (int m0 = 0; m0 < 64; m0 += 8) {
        float xa[8], xb[8], xc[8], xd[8], vf[8], yf[8];
        ldf8(p0 + m0, xa); ldf8(p1 + m0, xb);
        ldf8(p2 + m0, xc); ldf8(p3 + m0, xd);
        H8 yv = *(const H8*)(yrow + m0); unpackH8(yv, yf);
        ldf8(vp + m0, vf);
#pragma unroll
        for (int mm = 0; mm < 8; ++mm) {
          float z = tanh_fast(xa[mm] + xb[mm] + xc[mm] + xd[mm] + yf[mm]);
          lp = fmaf(z, vf[mm], lp);
        }
      }
      lpart[r][e4][t] = lp;
    } else {
      whh_gates();
    }
    __syncthreads();

    // ---- B2': per-wave redundant softmax + ct + ytil reduce (j<512) ----
    if (j < 512) {
      const int r = j >> 8, lane = j & 63;
      float l = lpart[r][0][lane] + lpart[r][1][lane] + lpart[r][2][lane] +
                lpart[r][3][lane];
      float mx = l;
#pragma unroll
      for (int off = 32; off; off >>= 1) mx = fmaxf(mx, __shfl_xor(mx, off, 64));
      float e = __builtin_amdgcn_exp2f((l - mx) * 1.4426950408889634f);
      float sm = e;
#pragma unroll
      for (int off = 32; off; off >>= 1) sm += __shfl_xor(sm, off, 64);
      betas16[wv][lane] = f2h(e * __builtin_amdgcn_rcpf(sm));
      asm volatile("s_waitcnt lgkmcnt(0)" ::: "memory");
      const u16* __restrict__ bp = betas16[wv];
      const u16* __restrict__ ep = &e16T[r][n * ES];
      float acc = 0.f;
#pragma unroll
      for (int t0 = 0; t0 < TT; t0 += 8) {
        H8 bv = *(const H8*)(bp + t0);
        h2 e0 = *(const h2*)(ep + t0);
        h2 e1 = *(const h2*)(ep + t0 + 2);
        h2 e2 = *(const h2*)(ep + t0 + 4);
        h2 e3 = *(const h2*)(ep + t0 + 6);
        acc = FDOT2(bv.p[0], e0, acc);
        acc = FDOT2(bv.p[1], e1, acc);
        acc = FDOT2(bv.p[2], e2, acc);
        acc = FDOT2(bv.p[3], e3, acc);
      }
      ((u16*)ctx16p[r])[n] = f2h(acc);
      float p = acc * wt_w[n];
#pragma unroll
      for (int off = 32; off; off >>= 1) p += __shfl_xor(p, off, 64);
      if ((j & 63) == 0) red[wv] = p;   // wv 0..3 -> r0, 4..7 -> r1
    }
    __syncthreads();

    // ---- G: combine pgs + gates (j<256, both rows) ----
    if (j < 256) {
      float yt0 = red[0] + red[1] + red[2] + red[3] + ysh[0][step] * wtM + wtb;
      float yt1 = red[4] + red[5] + red[6] + red[7] + ysh[1][step] * wtM + wtb;
      gates_combine_apply(yt0, yt1);
    }
    __syncthreads();
  }

  // ================= finals =================
  // ctdot from final f16 ct (same precision path as head)
  if (j < 512) {
    const int r = j >> 8;
    float p = h2f(((const u16*)ctx16p[r])[n]) * wt_w[n];
#pragma unroll
    for (int off = 32; off; off >>= 1) p += __shfl_xor(p, off, 64);
    if ((j & 63) == 0) red[wv] = p;
  }
  __syncthreads();
  const float ctd0 = red[0] + red[1] + red[2] + red[3];
  const float ctd1 = red[4] + red[5] + red[6] + red[7];

  head_store(0);  // y_Tp1 (sc[] holds it for train==0 feedback)

  const int tr = train[0];
  for (int e = 0; e < 2; ++e) {
    whh_gates();            // waves 8-15: Whh@h -> pgs
    __syncthreads();
    if (j < 256) {
      float inp0 = tr ? tar[(size_t)b0 * 2 + e] : sc[0];
      float inp1 = tr ? tar[(size_t)(b0 + 1) * 2 + e] : sc[1];
      float yt0 = ctd0 + inp0 * wtM + wtb;
      float yt1 = ctd1 + inp1 * wtM + wtb;
      gates_combine_apply(yt0, yt1);
    }
    __syncthreads();
    head_store(1 + e);
  }
}

extern "C" void kernel_launch(void* const* d_in, const int* in_sizes, int n_in,
                              void* d_out, int out_size, void* d_ws, size_t ws_size,
                              hipStream_t stream) {
  const float* E     = (const float*)d_in[0];
  const float* yin   = (const float*)d_in[1];
  const float* tar   = (const float*)d_in[2];
  const int*   train = (const int*)d_in[3];
  const float* Wd_w  = (const float*)d_in[4];
  const float* Wd_b  = (const float*)d_in[5];
  const float* Ud_w  = (const float*)d_in[6];
  const float* vd_w  = (const float*)d_in[7];
  const float* wt_w  = (const float*)d_in[8];
  const float* wt_b  = (const float*)d_in[9];
  const float* Wy_w  = (const float*)d_in[10];
  const float* Wy_b  = (const float*)d_in[11];
  const float* vy_w  = (const float*)d_in[12];
  const float* vy_b  = (const float*)d_in[13];
  const float* Wih   = (const float*)d_in[14];
  const float* Whh   = (const float*)d_in[15];
  const float* bih   = (const float*)d_in[16];
  const float* bhh   = (const float*)d_in[17];

  float* out = (float*)d_out;

  if (ws_size >= (size_t)WQ_BYTES) {
    u16* wq = (u16*)d_ws;
    prep_kernel<<<dim3(WQ_ELEMS / 256), dim3(256), 0, stream>>>(
        Wd_w, Whh, Wy_w, wq);
    scan_kernel<1><<<dim3(BB / NROW), dim3(NTH), 0, stream>>>(
        E, yin, tar, train, wq + WD16_OFF, Wd_b, Ud_w, vd_w, wt_w, wt_b,
        wq + WY16_OFF, Wy_b, vy_w, vy_b, Wih, wq + WHH16_OFF, bih, bhh, out);
  } else {
    scan_kernel<0><<<dim3(BB / NROW), dim3(NTH), 0, stream>>>(
        E, yin, tar, train, Wd_w, Wd_b, Ud_w, vd_w, wt_w, wt_b,
        Wy_w, Wy_b, vy_w, vy_b, Wih, Whh, bih, bhh, out);
  }

  (void)in_sizes; (void)n_in; (void)out_size;
}

// Round 7
// 1046.444 us; speedup vs baseline: 3.4311x; 1.0302x over previous
//
#include <hip/hip_runtime.h>

// TemporalAttentionDecoder_three_step: B=512, T=64, M=P=256. in f32, out f32.
// R14: 1078us. VALU 52%, occ 48%, no spill. Hiding Whh stream under B1 bought
//      ~1% -> stream never dominated. Falsified: occupancy(R10), traffic(R9),
//      coalescing(R11/12), stream latency(R14). Remaining: serial per-step
//      dependency tail h->x1->l->softmax->ct->ytil->gates across 4 barrier
//      phases (LDS round trips + shfl chains, few waves active).
// R15: algebraic shortening. ct only enters the scan via ct.wt (scalar), and
//      ct.wt = sum_t beta[t]*ew[t] with ew[t]=E[t].wt LOOP-INVARIANT. So:
//      (1) B2 (ct) deleted from all steps; ytil = (Σ e*ew)/(Σ e) -- both sums
//          share one butterfly; beta stays f32 (better precision).
//      (2) softmax+ytil+gates fused: waves 0-3 in-wave (lane=t) both rows ->
//          3 barriers/step; betas16/e16T off the critical path.
//      (3) final ct/ctx16p/ctd computed ONCE after the loop from last lpart.
//      (4) gate partials packed u32 (8 b32 reads in gates, was 16 u16).
// f32 state: creg (j<256); f16: h,c,y1,E,ct,weights; dots accumulate f32.

typedef unsigned short u16;
typedef unsigned int u32;
typedef _Float16 half_t;
typedef half_t h2 __attribute__((ext_vector_type(2)));

#define BB 512
#define TT 64
#define MM 256
#define YS 264   // y1l row stride (u16); measured conflict-free (R6/R7)
#define ES 68    // e16T row stride (u16); 2-way (free)
#define NROW 2
#define NTH 1024

// ws layout (u16), all k-blocked n-major [kb][n][8]:
//   WdT8 [64kb][256n][8]  @ 0       (131072)
//   WhhT8[32kb][1024n][8] @ 131072  (262144)
//   WyT8 [64kb][256n][8]  @ 393216  (131072)
#define WD16_OFF  0
#define WHH16_OFF 131072
#define WY16_OFF  393216
#define WQ_ELEMS  524288
#define WQ_BYTES  (WQ_ELEMS * 2)

struct H8 { h2 p[4]; };   // 16B = 8 f16

#if defined(__has_builtin)
#if __has_builtin(__builtin_amdgcn_fdot2)
#define FDOT2(a, b, c) __builtin_amdgcn_fdot2((a), (b), (c), false)
#endif
#endif
#ifndef FDOT2
__device__ __forceinline__ float FDOT2(h2 a, h2 b, float c) {
  return c + (float)a[0] * (float)b[0] + (float)a[1] * (float)b[1];
}
#endif

__device__ __forceinline__ float dot8(const H8 w, const H8 a, float acc) {
  acc = FDOT2(w.p[0], a.p[0], acc);
  acc = FDOT2(w.p[1], a.p[1], acc);
  acc = FDOT2(w.p[2], a.p[2], acc);
  acc = FDOT2(w.p[3], a.p[3], acc);
  return acc;
}
__device__ __forceinline__ u16 f2h(float f) {
  union { half_t h; u16 u; } x; x.h = (half_t)f; return x.u;
}
__device__ __forceinline__ float h2f(u16 u) {
  union { u16 u; half_t h; } x; x.u = u; return (float)x.h;
}
__device__ __forceinline__ u32 pack2h(float a, float b) {
  union { h2 h; u32 u; } x;
  x.h[0] = (half_t)a; x.h[1] = (half_t)b;
  return x.u;
}
__device__ __forceinline__ h2 u2h2(u32 u) {
  union { u32 u; h2 h; } x; x.u = u; return x.h;
}
__device__ __forceinline__ void unpackH8(const H8 v, float f[8]) {
#pragma unroll
  for (int i = 0; i < 8; ++i) f[i] = (float)v.p[i >> 1][i & 1];
}
__device__ __forceinline__ void ldf8(const float* p, float f[8]) {
  float4 a = *(const float4*)p;
  float4 b = *(const float4*)(p + 4);
  f[0]=a.x; f[1]=a.y; f[2]=a.z; f[3]=a.w;
  f[4]=b.x; f[5]=b.y; f[6]=b.z; f[7]=b.w;
}
__device__ __forceinline__ float tanh_fast(float x) {
  float e = __builtin_amdgcn_exp2f(x * 2.885390081777927f);
  return 1.0f - 2.0f * __builtin_amdgcn_rcpf(1.0f + e);
}
__device__ __forceinline__ float sigmoid_fast(float x) {
  float e = __builtin_amdgcn_exp2f(x * -1.4426950408889634f);
  return __builtin_amdgcn_rcpf(1.0f + e);
}

// ---- prep: f32 -> f16, k-blocked n-major ----
__global__ __launch_bounds__(256) void prep_kernel(
    const float* __restrict__ Wd, const float* __restrict__ Whh,
    const float* __restrict__ Wy, u16* __restrict__ o) {
  int i = blockIdx.x * 256 + threadIdx.x;   // 0..524287
  float v;
  if (i < WHH16_OFF) {
    int ki = i & 7, n = (i >> 3) & 255, kb = i >> 11;
    v = Wd[n * 512 + kb * 8 + ki];
  } else if (i < WY16_OFF) {
    int r = i - WHH16_OFF;
    int ki = r & 7, n = (r >> 3) & 1023, kb = r >> 13;
    v = Whh[n * 256 + kb * 8 + ki];
  } else {
    int r = i - WY16_OFF;
    int ki = r & 7, n = (r >> 3) & 255, kb = r >> 11;
    v = Wy[n * 512 + kb * 8 + ki];
  }
  o[i] = f2h(v);
}

template <int WQ>
__global__ __launch_bounds__(NTH, 4) void scan_kernel(
    const float* __restrict__ E,      // (B,T,M)
    const float* __restrict__ yin,    // (B,T,1)
    const float* __restrict__ tar,    // (B,2)
    const int*   __restrict__ train,  // (1)
    const void*  __restrict__ Wd_q,   // WQ1: WdT8 f16 | WQ0: f32 row-major
    const float* __restrict__ Wd_b,
    const float* __restrict__ Ud_w,   // (256,256) f32
    const float* __restrict__ vd_w,
    const float* __restrict__ wt_w,   // (257)
    const float* __restrict__ wt_b,
    const void*  __restrict__ Wy_q,
    const float* __restrict__ Wy_b,
    const float* __restrict__ vy_w,
    const float* __restrict__ vy_b,
    const float* __restrict__ Wih,    // (1024)
    const void*  __restrict__ Whh_q,
    const float* __restrict__ bih,
    const float* __restrict__ bhh,
    float* __restrict__ out)          // (3*B)
{
  __shared__ __align__(16) u16   y1l[NROW][TT * YS];   // 66KB f16 y1
  __shared__ __align__(16) u16   e16T[NROW][MM * ES];  // 68KB f16 E^T
  __shared__ __align__(16) u32   hs16[NROW][256];      // h pairs [0,128), c [128,256)
  __shared__ __align__(16) u32   ctx16p[NROW][128];    // ct f16 pairs
  __shared__ __align__(16) float px1[8][MM];   // x1 quarters [(r<<2)|q]; head reuse
  __shared__ __align__(16) u32   pgs32[8][MM]; // gate partials [(g<<1)|half], r0|r1<<16
  __shared__ __align__(16) float lpart[NROW][4][TT];
  __shared__ __align__(16) u16   betas16[8][TT];       // final ct only
  __shared__ __align__(16) float ysh[NROW][TT];
  __shared__ __align__(16) float ewl[NROW][TT];        // ew[t] = E[t].wt
  __shared__ float red[16];
  __shared__ float sc[NROW];

  const int j   = threadIdx.x;         // 0..1023
  const int n   = j & 255;             // output index
  const int grp = j >> 8;              // group 0..3 (wave-aligned)
  const int wv  = j >> 6;              // wave 0..15
  const int b0  = blockIdx.x * NROW;   // batch rows b0, b0+1

  if (j < 512) ((u32*)hs16)[j] = 0;
  float creg0 = 0.f, creg1 = 0.f;      // live in j<256 threads

  // gate constants (consumed by j<256)
  const float wih0 = Wih[n],       wih1 = Wih[n + 256];
  const float wih2 = Wih[n + 512], wih3 = Wih[n + 768];
  const float bb0 = bih[n]       + bhh[n];
  const float bb1 = bih[n + 256] + bhh[n + 256];
  const float bb2 = bih[n + 512] + bhh[n + 512];
  const float bb3 = bih[n + 768] + bhh[n + 768];
  const float wtM = wt_w[MM], wtb = wt_b[0];

  // ---- stage yin rows + ew[t] = E[t].wt (loop-invariant) ----
  if (j < NROW * TT) {
    const int r = j >> 6, t = j & 63;
    ysh[r][t] = yin[(size_t)(b0 + r) * TT + t];
    const float* __restrict__ Er = E + ((size_t)(b0 + r) * TT + t) * MM;
    float acc = 0.f;
    for (int m0 = 0; m0 < MM; m0 += 8) {
      float e[8], w[8];
      ldf8(Er + m0, e); ldf8(wt_w + m0, w);
#pragma unroll
      for (int m = 0; m < 8; ++m) acc = fmaf(e[m], w[m], acc);
    }
    ewl[r][t] = acc;
  }

  // ---- stage E^T (f16) into LDS for both rows ----
  {
    const float* __restrict__ Eb0 = E + (size_t)b0 * TT * MM;
    for (int i = j; i < NROW * TT * MM; i += NTH) {
      int r = i >> 14;
      int idx = i & 16383;
      int t = idx >> 8, m = idx & 255;
      e16T[r][m * ES + t] = f2h(Eb0[i]);
    }
  }

  // ---- y1 into LDS: thread (grp,n): row grp>>1, t-half grp&1, column n ----
  {
    const int rs = grp >> 1, ths = grp & 1;
    const float* __restrict__ Eb = E + (size_t)(b0 + rs) * TT * MM;
    const float* __restrict__ Uj = Ud_w + (size_t)n * MM;
    for (int t0 = ths * 32; t0 < ths * 32 + 32; t0 += 16) {
      float acc[16];
#pragma unroll
      for (int i = 0; i < 16; ++i) acc[i] = 0.f;
      for (int m0 = 0; m0 < MM; m0 += 8) {
        float w[8]; ldf8(Uj + m0, w);
#pragma unroll
        for (int tt = 0; tt < 16; ++tt) {
          float e[8]; ldf8(Eb + (size_t)(t0 + tt) * MM + m0, e);
#pragma unroll
          for (int mm = 0; mm < 8; ++mm) acc[tt] = fmaf(e[mm], w[mm], acc[tt]);
        }
      }
#pragma unroll
      for (int tt = 0; tt < 16; ++tt)
        y1l[rs][(t0 + tt) * YS + n] = f2h(acc[tt]);
    }
  }
  __syncthreads();

  // ---- gates: torch LSTMCell order i,f,g,o; j<256 threads, both rows ----
  auto gates_apply = [&](int r, float gi, float gf, float gg, float go,
                         float ytil) {
    gi += ytil * wih0 + bb0;
    gf += ytil * wih1 + bb1;
    gg += ytil * wih2 + bb2;
    go += ytil * wih3 + bb3;
    float& cr = r ? creg1 : creg0;
    float c = sigmoid_fast(gf) * cr + sigmoid_fast(gi) * tanh_fast(gg);
    float h = sigmoid_fast(go) * tanh_fast(c);
    cr = c;
    u16* hsu = (u16*)hs16[r];
    hsu[n] = f2h(h);
    hsu[256 + n] = f2h(c);
  };

  // ---- S2: Whh@h all 4 gates x both rows; waves 8-15 only ----
  auto whh_gates = [&]() {
    if (wv >= 8) {
      const int jj = j - 512;
      const int n2 = jj & 255, half = jj >> 8;   // k-half
      float a00 = 0, a01 = 0, a10 = 0, a11 = 0;
      float a20 = 0, a21 = 0, a30 = 0, a31 = 0;
      if (WQ) {
        const u16* __restrict__ base =
            (const u16*)Whh_q + ((size_t)(half * 16) * 1024 + n2) * 8;
#pragma unroll 2
        for (int i = 0; i < 16; ++i) {
          const u16* p = base + (size_t)i * 8192;
          H8 w0 = *(const H8*)p;
          H8 w1 = *(const H8*)(p + 2048);
          H8 w2 = *(const H8*)(p + 4096);
          H8 w3 = *(const H8*)(p + 6144);
          const int kb = half * 16 + i;
          H8 h0v = *(const H8*)&hs16[0][kb * 4];
          H8 h1v = *(const H8*)&hs16[1][kb * 4];
          a00 = dot8(w0, h0v, a00); a01 = dot8(w0, h1v, a01);
          a10 = dot8(w1, h0v, a10); a11 = dot8(w1, h1v, a11);
          a20 = dot8(w2, h0v, a20); a21 = dot8(w2, h1v, a21);
          a30 = dot8(w3, h0v, a30); a31 = dot8(w3, h1v, a31);
        }
      } else {
        const float* __restrict__ base =
            (const float*)Whh_q + (size_t)n2 * 256 + half * 128;
#pragma unroll 2
        for (int i = 0; i < 16; ++i) {
          const int kb = half * 16 + i;
          H8 h0v = *(const H8*)&hs16[0][kb * 4];
          H8 h1v = *(const H8*)&hs16[1][kb * 4];
          float hf0[8], hf1[8]; unpackH8(h0v, hf0); unpackH8(h1v, hf1);
          float w0[8], w1[8], w2[8], w3[8];
          ldf8(base + i * 8, w0);
          ldf8(base + 256 * 256 + i * 8, w1);
          ldf8(base + 512 * 256 + i * 8, w2);
          ldf8(base + 768 * 256 + i * 8, w3);
#pragma unroll
          for (int m = 0; m < 8; ++m) {
            a00 = fmaf(hf0[m], w0[m], a00); a01 = fmaf(hf1[m], w0[m], a01);
            a10 = fmaf(hf0[m], w1[m], a10); a11 = fmaf(hf1[m], w1[m], a11);
            a20 = fmaf(hf0[m], w2[m], a20); a21 = fmaf(hf1[m], w2[m], a21);
            a30 = fmaf(hf0[m], w3[m], a30); a31 = fmaf(hf1[m], w3[m], a31);
          }
        }
      }
      pgs32[(0 << 1) | half][n2] = pack2h(a00, a01);
      pgs32[(1 << 1) | half][n2] = pack2h(a10, a11);
      pgs32[(2 << 1) | half][n2] = pack2h(a20, a21);
      pgs32[(3 << 1) | half][n2] = pack2h(a30, a31);
    }
  };

  // ---- G: combine pgs32 halves + LSTM gates (j<256, both rows) ----
  auto gates_combine_apply = [&](float yt0, float yt1) {
    h2 i0 = u2h2(pgs32[0][n]), i1 = u2h2(pgs32[1][n]);
    h2 f0 = u2h2(pgs32[2][n]), f1 = u2h2(pgs32[3][n]);
    h2 g0 = u2h2(pgs32[4][n]), g1 = u2h2(pgs32[5][n]);
    h2 o0 = u2h2(pgs32[6][n]), o1 = u2h2(pgs32[7][n]);
    gates_apply(0, (float)i0[0] + (float)i1[0], (float)f0[0] + (float)f1[0],
                (float)g0[0] + (float)g1[0], (float)o0[0] + (float)o1[0], yt0);
    gates_apply(1, (float)i0[1] + (float)i1[1], (float)f0[1] + (float)f1[1],
                (float)g0[1] + (float)g1[1], (float)o0[1] + (float)o1[1], yt1);
  };

  // ---- head: grp = (row<<1)|seg; seg0 = h-seg, seg1 = ct-seg ----
  auto head_store = [&](int outIdx) {
    float p = 0.f;
    const int rr = grp >> 1, seg = grp & 1;
    const u32* st = seg ? ctx16p[rr] : hs16[rr];
    if (WQ) {
      const u16* pw = (const u16*)Wy_q + ((size_t)(seg * 32) * 256 + n) * 8;
#pragma unroll 2
      for (int kb = 0; kb < 32; ++kb) {
        H8 w = *(const H8*)pw; pw += 2048;
        H8 s = *(const H8*)&st[kb * 4];
        p = dot8(w, s, p);
      }
    } else {
      const float* W = (const float*)Wy_q + (size_t)n * 512 + seg * 256;
#pragma unroll 2
      for (int kb = 0; kb < 32; ++kb) {
        H8 sv = *(const H8*)&st[kb * 4];
        float sf[8]; unpackH8(sv, sf);
        float w[8]; ldf8(W + kb * 8, w);
#pragma unroll
        for (int i = 0; i < 8; ++i) p = fmaf(sf[i], w[i], p);
      }
    }
    if (grp) px1[grp - 1][n] = p;   // px1 free after scan; reuse as head parts
    __syncthreads();
    if (grp == 0) {
      float q0 = (p + px1[0][n] + Wy_b[n]) * vy_w[n];
      float q1 = (px1[1][n] + px1[2][n] + Wy_b[n]) * vy_w[n];
#pragma unroll
      for (int off = 32; off; off >>= 1) {
        q0 += __shfl_xor(q0, off, 64);
        q1 += __shfl_xor(q1, off, 64);
      }
      if ((j & 63) == 0) { red[wv] = q0; red[4 + wv] = q1; }
    }
    __syncthreads();
    if (j == 0) {
      float o0 = red[0] + red[1] + red[2] + red[3] + vy_b[0];
      float o1 = red[4] + red[5] + red[6] + red[7] + vy_b[0];
      out[(size_t)outIdx * BB + b0] = o0;
      out[(size_t)outIdx * BB + b0 + 1] = o1;
      sc[0] = o0; sc[1] = o1;
    }
    __syncthreads();
  };

  // ================= scan over T steps =================
  for (int step = 0; step < TT; ++step) {
    // ---- S1: x1 = Wd.[h|c], 4-way split-k (all waves) ----
    {
      float ax0 = 0.f, ax1 = 0.f;
      if (WQ) {
        const u16* pd = (const u16*)Wd_q + ((size_t)(grp * 16) * 256 + n) * 8;
#pragma unroll 4
        for (int i = 0; i < 16; ++i) {
          H8 w = *(const H8*)pd; pd += 2048;
          const int kb = grp * 16 + i;
          H8 s0 = *(const H8*)&hs16[0][kb * 4];
          H8 s1 = *(const H8*)&hs16[1][kb * 4];
          ax0 = dot8(w, s0, ax0);
          ax1 = dot8(w, s1, ax1);
        }
      } else {
        const float* pd = (const float*)Wd_q + (size_t)n * 512 + grp * 128;
#pragma unroll 2
        for (int i = 0; i < 16; ++i) {
          const int kb = grp * 16 + i;
          H8 s0v = *(const H8*)&hs16[0][kb * 4];
          H8 s1v = *(const H8*)&hs16[1][kb * 4];
          float f0[8], f1[8]; unpackH8(s0v, f0); unpackH8(s1v, f1);
          float w[8]; ldf8(pd + i * 8, w);
#pragma unroll
          for (int m = 0; m < 8; ++m) {
            ax0 = fmaf(f0[m], w[m], ax0);
            ax1 = fmaf(f1[m], w[m], ax1);
          }
        }
      }
      if (grp == 0) { float b = Wd_b[n]; ax0 += b; ax1 += b; }
      px1[grp][n] = ax0;
      px1[4 + grp][n] = ax1;
    }
    __syncthreads();

    // ---- B1 (waves 0-7) PARALLEL S2 (waves 8-15) ----
    if (wv < 8) {
      const int r = j >> 8, e4 = (j >> 6) & 3, t = j & 63;
      const int mb = e4 * 64;
      const u16* __restrict__ yrow = &y1l[r][t * YS + mb];
      const float* __restrict__ p0 = &px1[(r << 2) | 0][mb];
      const float* __restrict__ p1 = &px1[(r << 2) | 1][mb];
      const float* __restrict__ p2 = &px1[(r << 2) | 2][mb];
      const float* __restrict__ p3 = &px1[(r << 2) | 3][mb];
      const float* __restrict__ vp = vd_w + mb;
      float lp = 0.f;
#pragma unroll 2
      for (int m0 = 0; m0 < 64; m0 += 8) {
        float xa[8], xb[8], xc[8], xd[8], vf[8], yf[8];
        ldf8(p0 + m0, xa); ldf8(p1 + m0, xb);
        ldf8(p2 + m0, xc); ldf8(p3 + m0, xd);
        H8 yv = *(const H8*)(yrow + m0); unpackH8(yv, yf);
        ldf8(vp + m0, vf);
#pragma unroll
        for (int mm = 0; mm < 8; ++mm) {
          float z = tanh_fast(xa[mm] + xb[mm] + xc[mm] + xd[mm] + yf[mm]);
          lp = fmaf(z, vf[mm], lp);
        }
      }
      lpart[r][e4][t] = lp;
    } else {
      whh_gates();
    }
    __syncthreads();

    // ---- SMG: in-wave softmax + ytil + gates (waves 0-3, both rows) ----
    if (j < 256) {
      const int t = j & 63;
      float l0 = lpart[0][0][t] + lpart[0][1][t] + lpart[0][2][t] +
                 lpart[0][3][t];
      float l1 = lpart[1][0][t] + lpart[1][1][t] + lpart[1][2][t] +
                 lpart[1][3][t];
      float m0v = l0, m1v = l1;
#pragma unroll
      for (int off = 32; off; off >>= 1) {
        m0v = fmaxf(m0v, __shfl_xor(m0v, off, 64));
        m1v = fmaxf(m1v, __shfl_xor(m1v, off, 64));
      }
      float e0 = __builtin_amdgcn_exp2f((l0 - m0v) * 1.4426950408889634f);
      float e1 = __builtin_amdgcn_exp2f((l1 - m1v) * 1.4426950408889634f);
      float se0 = e0, sy0 = e0 * ewl[0][t];
      float se1 = e1, sy1 = e1 * ewl[1][t];
#pragma unroll
      for (int off = 32; off; off >>= 1) {
        se0 += __shfl_xor(se0, off, 64); sy0 += __shfl_xor(sy0, off, 64);
        se1 += __shfl_xor(se1, off, 64); sy1 += __shfl_xor(sy1, off, 64);
      }
      float yt0 = sy0 * __builtin_amdgcn_rcpf(se0) + ysh[0][step] * wtM + wtb;
      float yt1 = sy1 * __builtin_amdgcn_rcpf(se1) + ysh[1][step] * wtM + wtb;
      gates_combine_apply(yt0, yt1);
    }
    __syncthreads();
  }

  // ================= finals =================
  // FINAL-B2: beta (f16) + ct -> ctx16p from last step's lpart (j<512)
  if (j < 512) {
    const int r = j >> 8, lane = j & 63;
    float l = lpart[r][0][lane] + lpart[r][1][lane] + lpart[r][2][lane] +
              lpart[r][3][lane];
    float mx = l;
#pragma unroll
    for (int off = 32; off; off >>= 1) mx = fmaxf(mx, __shfl_xor(mx, off, 64));
    float e = __builtin_amdgcn_exp2f((l - mx) * 1.4426950408889634f);
    float sm = e;
#pragma unroll
    for (int off = 32; off; off >>= 1) sm += __shfl_xor(sm, off, 64);
    betas16[wv][lane] = f2h(e * __builtin_amdgcn_rcpf(sm));
    asm volatile("s_waitcnt lgkmcnt(0)" ::: "memory");
    const u16* __restrict__ bp = betas16[wv];
    const u16* __restrict__ ep = &e16T[r][n * ES];
    float acc = 0.f;
#pragma unroll
    for (int t0 = 0; t0 < TT; t0 += 8) {
      H8 bv = *(const H8*)(bp + t0);
      h2 e0 = *(const h2*)(ep + t0);
      h2 e1 = *(const h2*)(ep + t0 + 2);
      h2 e2 = *(const h2*)(ep + t0 + 4);
      h2 e3 = *(const h2*)(ep + t0 + 6);
      acc = FDOT2(bv.p[0], e0, acc);
      acc = FDOT2(bv.p[1], e1, acc);
      acc = FDOT2(bv.p[2], e2, acc);
      acc = FDOT2(bv.p[3], e3, acc);
    }
    ((u16*)ctx16p[r])[n] = f2h(acc);
  }
  __syncthreads();

  // ctdot from final f16 ct (same precision path as head)
  if (j < 512) {
    const int r = j >> 8;
    float p = h2f(((const u16*)ctx16p[r])[n]) * wt_w[n];
#pragma unroll
    for (int off = 32; off; off >>= 1) p += __shfl_xor(p, off, 64);
    if ((j & 63) == 0) red[wv] = p;
  }
  __syncthreads();
  const float ctd0 = red[0] + red[1] + red[2] + red[3];
  const float ctd1 = red[4] + red[5] + red[6] + red[7];

  head_store(0);  // y_Tp1 (sc[] holds it for train==0 feedback)

  const int tr = train[0];
  for (int e = 0; e < 2; ++e) {
    whh_gates();            // waves 8-15: Whh@h -> pgs32
    __syncthreads();
    if (j < 256) {
      float inp0 = tr ? tar[(size_t)b0 * 2 + e] : sc[0];
      float inp1 = tr ? tar[(size_t)(b0 + 1) * 2 + e] : sc[1];
      float yt0 = ctd0 + inp0 * wtM + wtb;
      float yt1 = ctd1 + inp1 * wtM + wtb;
      gates_combine_apply(yt0, yt1);
    }
    __syncthreads();
    head_store(1 + e);
  }
}

extern "C" void kernel_launch(void* const* d_in, const int* in_sizes, int n_in,
                              void* d_out, int out_size, void* d_ws, size_t ws_size,
                              hipStream_t stream) {
  const float* E     = (const float*)d_in[0];
  const float* yin   = (const float*)d_in[1];
  const float* tar   = (const float*)d_in[2];
  const int*   train = (const int*)d_in[3];
  const float* Wd_w  = (const float*)d_in[4];
  const float* Wd_b  = (const float*)d_in[5];
  const float* Ud_w  = (const float*)d_in[6];
  const float* vd_w  = (const float*)d_in[7];
  const float* wt_w  = (const float*)d_in[8];
  const float* wt_b  = (const float*)d_in[9];
  const float* Wy_w  = (const float*)d_in[10];
  const float* Wy_b  = (const float*)d_in[11];
  const float* vy_w  = (const float*)d_in[12];
  const float* vy_b  = (const float*)d_in[13];
  const float* Wih   = (const float*)d_in[14];
  const float* Whh   = (const float*)d_in[15];
  const float* bih   = (const float*)d_in[16];
  const float* bhh   = (const float*)d_in[17];

  float* out = (float*)d_out;

  if (ws_size >= (size_t)WQ_BYTES) {
    u16* wq = (u16*)d_ws;
    prep_kernel<<<dim3(WQ_ELEMS / 256), dim3(256), 0, stream>>>(
        Wd_w, Whh, Wy_w, wq);
    scan_kernel<1><<<dim3(BB / NROW), dim3(NTH), 0, stream>>>(
        E, yin, tar, train, wq + WD16_OFF, Wd_b, Ud_w, vd_w, wt_w, wt_b,
        wq + WY16_OFF, Wy_b, vy_w, vy_b, Wih, wq + WHH16_OFF, bih, bhh, out);
  } else {
    scan_kernel<0><<<dim3(BB / NROW), dim3(NTH), 0, stream>>>(
        E, yin, tar, train, Wd_w, Wd_b, Ud_w, vd_w, wt_w, wt_b,
        Wy_w, Wy_b, vy_w, vy_b, Wih, Whh, bih, bhh, out);
  }

  (void)in_sizes; (void)n_in; (void)out_size;
}